// Round 10
// baseline (349.607 us; speedup 1.0000x reference)
//
#include <hip/hip_runtime.h>
#include <hip/hip_bf16.h>
#include <math.h>

// ---------------------------------------------------------------------------
// EncoderBlock, bf16-MFMA, round 10: fusion round.
//  - v-transpose folded into QKV GEMM epilogue (n>=2048 tiles store ushort4
//    straight into vT[hd][token]); vtrans + corrp/corr_reduce dropped
//  - masksum kernel (round-5 style, reads vT once) supplies corr
//  - LN1 merged into the wconv launch (independent blocks, one dispatch)
//  - GEMM/attention structure otherwise as round 9
// ---------------------------------------------------------------------------

#define EPS 1e-5f

typedef __attribute__((ext_vector_type(8))) short bf16x8;
typedef __attribute__((ext_vector_type(4))) float f32x4;

typedef const __attribute__((address_space(1))) unsigned char glob_byte;
typedef __attribute__((address_space(3))) unsigned char lds_byte;

__device__ __forceinline__ void g2l16(const void* g, void* l) {
  __builtin_amdgcn_global_load_lds((glob_byte*)g, (lds_byte*)l, 16, 0, 0);
}

__device__ __forceinline__ unsigned short f2bf(float f) {
  union { float f; unsigned int u; } v; v.f = f;
  return (unsigned short)((v.u + 0x7FFFu + ((v.u >> 16) & 1u)) >> 16);
}
__device__ __forceinline__ float bf2f(unsigned short b) {
  union { unsigned int u; float f; } v; v.u = (unsigned int)b << 16;
  return v.f;
}
__device__ __forceinline__ unsigned int fbits(float f) {
  union { float f; unsigned int u; } v; v.f = f;
  return v.u;
}

// ---- weights fp32 [K][N] -> bf16 [N][K] (bid<3072); qkv bias (bid==3072);
// LN1 rows (bid>=3073): xn = LN(x) bf16.
__global__ __launch_bounds__(256) void wconv_ln_kernel(
    const float* __restrict__ wq, const float* __restrict__ wk,
    const float* __restrict__ wv, const float* __restrict__ wo,
    const float* __restrict__ w1, const float* __restrict__ w2,
    const float* __restrict__ bq, const float* __restrict__ bk,
    const float* __restrict__ bv,
    unsigned short* __restrict__ wqkvT, unsigned short* __restrict__ woT,
    unsigned short* __restrict__ w1T, unsigned short* __restrict__ w2T,
    float* __restrict__ bqkv,
    const float* __restrict__ x, unsigned short* __restrict__ xn,
    const float* __restrict__ ln1a, const float* __restrict__ ln1b) {
  __shared__ float tile[64][65];
  const int bid = blockIdx.x;
  const int t = threadIdx.x;
  if (bid >= 3073) {  // ---- LayerNorm (torch: ddof=1, /(std+eps))
    const int row = bid - 3073;
    const float4 v = ((const float4*)(x + (size_t)row * 1024))[t];
    float s  = v.x + v.y + v.z + v.w;
    float ss = v.x * v.x + v.y * v.y + v.z * v.z + v.w * v.w;
#pragma unroll
    for (int off = 32; off > 0; off >>= 1) {
      s  += __shfl_down(s, off, 64);
      ss += __shfl_down(ss, off, 64);
    }
    __shared__ float red[8];
    const int lane = t & 63, wv_ = t >> 6;
    if (lane == 0) { red[wv_] = s; red[4 + wv_] = ss; }
    __syncthreads();
    const float S  = red[0] + red[1] + red[2] + red[3];
    const float SS = red[4] + red[5] + red[6] + red[7];
    const float mean = S * (1.0f / 1024.0f);
    float var = (SS - 1024.0f * mean * mean) * (1.0f / 1023.0f);
    var = fmaxf(var, 0.0f);
    const float scl = ln1a[0] / (sqrtf(var) + EPS);
    const float b = ln1b[0];
    ushort4 o;
    o.x = f2bf((v.x - mean) * scl + b);
    o.y = f2bf((v.y - mean) * scl + b);
    o.z = f2bf((v.z - mean) * scl + b);
    o.w = f2bf((v.w - mean) * scl + b);
    ((ushort4*)(xn + (size_t)row * 1024))[t] = o;
    return;
  }
  if (bid == 3072) {  // ---- fused qkv bias
#pragma unroll
    for (int i = 0; i < 12; ++i) {
      const int n = i * 256 + t;
      bqkv[n] = n < 1024 ? bq[n] : (n < 2048 ? bk[n - 1024] : bv[n - 2048]);
    }
    return;
  }
  // ---- weight transpose+cast
  const float* src; unsigned short* dst; int K, N, tk, tn;
  if (bid < 1024) {
    const int m = bid >> 8, loc = bid & 255;
    src = m == 0 ? wq : m == 1 ? wk : m == 2 ? wv : wo;
    dst = m == 3 ? woT : (wqkvT + (size_t)m * 1024 * 1024);
    K = 1024; N = 1024; tk = loc >> 4; tn = loc & 15;
  } else if (bid < 2048) {
    const int loc = bid - 1024; src = w1; dst = w1T;
    K = 1024; N = 4096; tk = loc >> 6; tn = loc & 63;
  } else {
    const int loc = bid - 2048; src = w2; dst = w2T;
    K = 4096; N = 1024; tk = loc >> 4; tn = loc & 15;
  }
  const int lr = t >> 4, lc = (t & 15) * 4;
#pragma unroll
  for (int i = 0; i < 4; ++i) {
    const float4 v = *(const float4*)(src + (size_t)(tk * 64 + lr + 16 * i) * N + tn * 64 + lc);
    tile[lr + 16 * i][lc + 0] = v.x;
    tile[lr + 16 * i][lc + 1] = v.y;
    tile[lr + 16 * i][lc + 2] = v.z;
    tile[lr + 16 * i][lc + 3] = v.w;
  }
  __syncthreads();
  const int on = t >> 2, ok = (t & 3) * 16;
#pragma unroll
  for (int jj = 0; jj < 4; ++jj) {
    ushort4 o4;
    o4.x = f2bf(tile[ok + 4 * jj + 0][on]);
    o4.y = f2bf(tile[ok + 4 * jj + 1][on]);
    o4.z = f2bf(tile[ok + 4 * jj + 2][on]);
    o4.w = f2bf(tile[ok + 4 * jj + 3][on]);
    *(ushort4*)(dst + (size_t)(tn * 64 + on) * K + tk * 64 + ok + 4 * jj) = o4;
  }
}

// ---- bf16 MFMA GEMM, BK=64. A:[M][lda], Bt:[N][ldb] bf16 row-major,
// 128x128 tile. SPLITK: gridDim.z slices of KH -> bf16 partial Cz.
// VSPLIT: tiles with n0>=2048 store TRANSPOSED (+bias) into C1 = vT[hd][tok].
// RX/RY: 2D L2-region swizzle (nrx*nry*gz == 8).
template <int TM, int TN, bool OUT_BF16, bool RELU, bool SPLITK, bool VSPLIT,
          int RX, int RY>
__global__ __launch_bounds__(256, 4) void mfma_gemm(
    const unsigned short* __restrict__ A, const unsigned short* __restrict__ Bt,
    const float* __restrict__ bias,
    void* __restrict__ C0, void* __restrict__ C1,
    void* __restrict__ C2, void* __restrict__ C3,
    int N, int lda, int ldb, int KH) {
  constexpr int WM = 2, WN = 2;
  constexpr int MSPAN = TM / WM, NSPAN = TN / WN;
  constexpr int MI = MSPAN / 16, NJ = NSPAN / 16;
  __shared__ __align__(16) unsigned short As[TM * 64];
  __shared__ __align__(16) unsigned short Bs[TN * 64];
  const int tid = threadIdx.x, lane = tid & 63;
  const int w = tid >> 6;
  const int quad = lane >> 4, col = lane & 15;
  const int wm = w % WM, wn = w / WM;

  int bx = blockIdx.x, by = blockIdx.y, bz = blockIdx.z;
  {
    const int gx = gridDim.x, gy = gridDim.y;
    const int L = bx + gx * (by + gy * bz);
    const int r = L & 7, s = L >> 3;
    const int nrx = gx / RX, nry = gy / RY;
    const int rx = r % nrx, rem = r / nrx;
    const int ry = rem % nry, rz = rem / nry;
    bx = rx * RX + s % RX;
    by = ry * RY + (s / RX) % RY;
    bz = rz;
  }
  const int m0 = by * TM, n0 = bx * TN;
  const int koff = SPLITK ? bz * KH : 0;

  f32x4 acc[MI][NJ];
  const f32x4 z4 = {0.f, 0.f, 0.f, 0.f};
#pragma unroll
  for (int i = 0; i < MI; ++i)
#pragma unroll
    for (int j = 0; j < NJ; ++j) acc[i][j] = z4;

  for (int k0 = 0; k0 < KH; k0 += 64) {
    __syncthreads();
#pragma unroll
    for (int t = 0; t < TM / 32; ++t) {
      const int s = t * 256 + tid;
      const int r = s >> 3, c = (s & 7) ^ (r & 7);
      g2l16(A + (size_t)(m0 + r) * lda + koff + k0 + c * 8, (void*)(As + s * 8));
    }
#pragma unroll
    for (int t = 0; t < TN / 32; ++t) {
      const int s = t * 256 + tid;
      const int r = s >> 3, c = (s & 7) ^ (r & 7);
      g2l16(Bt + (size_t)(n0 + r) * ldb + koff + k0 + c * 8, (void*)(Bs + s * 8));
    }
    __syncthreads();
#pragma unroll
    for (int h = 0; h < 2; ++h) {
      bf16x8 af[MI], bfr[NJ];
#pragma unroll
      for (int i = 0; i < MI; ++i) {
        const int rr = wm * MSPAN + i * 16 + col;
        af[i] = *(const bf16x8*)(As + rr * 64 + (((h << 2) | quad) ^ (rr & 7)) * 8);
      }
#pragma unroll
      for (int j = 0; j < NJ; ++j) {
        const int rr = wn * NSPAN + j * 16 + col;
        bfr[j] = *(const bf16x8*)(Bs + rr * 64 + (((h << 2) | quad) ^ (rr & 7)) * 8);
      }
#pragma unroll
      for (int i = 0; i < MI; ++i)
#pragma unroll
        for (int j = 0; j < NJ; ++j)
          acc[i][j] = __builtin_amdgcn_mfma_f32_16x16x32_bf16(af[i], bfr[j], acc[i][j], 0, 0, 0);
    }
  }
#pragma unroll
  for (int i = 0; i < MI; ++i) {
    const int mrow = m0 + wm * MSPAN + i * 16 + quad * 4;
#pragma unroll
    for (int j = 0; j < NJ; ++j) {
      const int n = n0 + wn * NSPAN + j * 16 + col;
      const float bn = SPLITK ? 0.f : bias[n];
      if (VSPLIT && n0 >= 2048) {
        // v-tile: transposed store, 4 consecutive tokens -> one ushort4
        ushort4 o4;
        o4.x = f2bf(acc[i][j][0] + bn);
        o4.y = f2bf(acc[i][j][1] + bn);
        o4.z = f2bf(acc[i][j][2] + bn);
        o4.w = f2bf(acc[i][j][3] + bn);
        *(ushort4*)((unsigned short*)C1 + (size_t)(n - 2048) * 4096 + mrow) = o4;
        continue;
      }
#pragma unroll
      for (int r = 0; r < 4; ++r) {
        const int m = mrow + r;
        if (SPLITK) {
          unsigned short* P = bz == 0 ? (unsigned short*)C0
                            : bz == 1 ? (unsigned short*)C1
                            : bz == 2 ? (unsigned short*)C2
                                      : (unsigned short*)C3;
          P[(size_t)m * N + n] = f2bf(acc[i][j][r]);
        } else {
          float v = acc[i][j][r] + bn;
          if (RELU) v = fmaxf(v, 0.f);
          if (OUT_BF16) ((unsigned short*)C0)[(size_t)m * N + n] = f2bf(v);
          else          ((float*)C0)[(size_t)m * N + n] = v;
        }
      }
    }
  }
}

// ---- corr[b*1024+hd] = sum_{tok: mask==0} V[tok][hd]  (raw sum; combine
// applies -1e9). One block per (hd-group 64, batch).
__global__ __launch_bounds__(256) void masksum_kernel(
    const unsigned short* __restrict__ vT, const int* __restrict__ mask,
    float* __restrict__ corr) {
  const int hg = blockIdx.x, b = blockIdx.y, t = threadIdx.x;
  const int hd = hg * 64 + (t & 63), sg = t >> 6;
  const int* mrow = mask + b * 1024 + sg * 256;
  const unsigned short* vrow = vT + (size_t)hd * 4096 + b * 1024 + sg * 256;
  float s = 0.f;
  for (int i = 0; i < 256; ++i)
    if (mrow[i] == 0) s += bf2f(vrow[i]);
  __shared__ float red[4][64];
  red[sg][t & 63] = s;
  __syncthreads();
  if (sg == 0)
    corr[b * 1024 + hd] = red[0][t] + red[1][t] + red[2][t] + red[3][t];
}

// ---- combine wo partials (bf16) + x + bo -> x1 (bf16) ; xn2 = LN2.
__global__ __launch_bounds__(256) void combine_ln_kernel(
    const unsigned short* __restrict__ p0, const unsigned short* __restrict__ p1,
    const float* __restrict__ x, const float* __restrict__ bo,
    const float* __restrict__ alpha, const float* __restrict__ beta,
    unsigned short* __restrict__ x1, unsigned short* __restrict__ xn2) {
  const int row = blockIdx.x, t = threadIdx.x;
  const size_t i = (size_t)row * 256 + t;
  const ushort4 a4 = ((const ushort4*)p0)[i];
  const ushort4 b4 = ((const ushort4*)p1)[i];
  const float4 x4 = ((const float4*)x)[i];
  const float4 o4 = ((const float4*)bo)[t];
  float4 v;
  v.x = bf2f(a4.x) + bf2f(b4.x) + x4.x + o4.x;
  v.y = bf2f(a4.y) + bf2f(b4.y) + x4.y + o4.y;
  v.z = bf2f(a4.z) + bf2f(b4.z) + x4.z + o4.z;
  v.w = bf2f(a4.w) + bf2f(b4.w) + x4.w + o4.w;
  ushort4 xb;
  xb.x = f2bf(v.x); xb.y = f2bf(v.y); xb.z = f2bf(v.z); xb.w = f2bf(v.w);
  ((ushort4*)x1)[i] = xb;
  float s  = v.x + v.y + v.z + v.w;
  float ss = v.x * v.x + v.y * v.y + v.z * v.z + v.w * v.w;
#pragma unroll
  for (int off = 32; off > 0; off >>= 1) {
    s  += __shfl_down(s, off, 64);
    ss += __shfl_down(ss, off, 64);
  }
  __shared__ float red[8];
  const int lane = t & 63, wv_ = t >> 6;
  if (lane == 0) { red[wv_] = s; red[4 + wv_] = ss; }
  __syncthreads();
  const float S  = red[0] + red[1] + red[2] + red[3];
  const float SS = red[4] + red[5] + red[6] + red[7];
  const float mean = S * (1.0f / 1024.0f);
  float var = (SS - 1024.0f * mean * mean) * (1.0f / 1023.0f);
  var = fmaxf(var, 0.0f);
  const float scl = alpha[0] / (sqrtf(var) + EPS);
  const float bb = beta[0];
  ushort4 o;
  o.x = f2bf((v.x - mean) * scl + bb);
  o.y = f2bf((v.y - mean) * scl + bb);
  o.z = f2bf((v.z - mean) * scl + bb);
  o.w = f2bf((v.w - mean) * scl + bb);
  ((ushort4*)xn2)[i] = o;
}

// ---- combine ffn2 partials (4x bf16) + x1 (bf16) + b2 -> out fp32.
__global__ __launch_bounds__(256) void combine_out_kernel(
    const unsigned short* __restrict__ pf0, const unsigned short* __restrict__ pf1,
    const unsigned short* __restrict__ pf2, const unsigned short* __restrict__ pf3,
    const unsigned short* __restrict__ x1, const float* __restrict__ b2,
    float* __restrict__ out) {
  const int t = threadIdx.x;
  const size_t i = (size_t)blockIdx.x * 256 + t;
  const ushort4 a4 = ((const ushort4*)pf0)[i];
  const ushort4 b4 = ((const ushort4*)pf1)[i];
  const ushort4 c4 = ((const ushort4*)pf2)[i];
  const ushort4 d4 = ((const ushort4*)pf3)[i];
  const ushort4 e4 = ((const ushort4*)x1)[i];
  const float4 f4 = ((const float4*)b2)[t];
  float4 v;
  v.x = bf2f(a4.x) + bf2f(b4.x) + bf2f(c4.x) + bf2f(d4.x) + bf2f(e4.x) + f4.x;
  v.y = bf2f(a4.y) + bf2f(b4.y) + bf2f(c4.y) + bf2f(d4.y) + bf2f(e4.y) + f4.y;
  v.z = bf2f(a4.z) + bf2f(b4.z) + bf2f(c4.z) + bf2f(d4.z) + bf2f(e4.z) + f4.z;
  v.w = bf2f(a4.w) + bf2f(b4.w) + bf2f(c4.w) + bf2f(d4.w) + bf2f(e4.w) + f4.w;
  ((float4*)out)[i] = v;
}

// ---- combine attention key-halves + corr -> ctx (bf16)
__global__ __launch_bounds__(256) void attn_combine_kernel(
    const unsigned short* __restrict__ p0, const unsigned short* __restrict__ p1,
    const float* __restrict__ corr, unsigned short* __restrict__ ctx) {
  const int row = blockIdx.x, t = threadIdx.x;
  const size_t i = (size_t)row * 256 + t;
  const ushort4 a4 = ((const ushort4*)p0)[i];
  const ushort4 b4 = ((const ushort4*)p1)[i];
  const float4 c4 = ((const float4*)(corr + (row >> 10) * 1024))[t];
  ushort4 o;
  o.x = f2bf(bf2f(a4.x) + bf2f(b4.x) - 1e9f * c4.x);
  o.y = f2bf(bf2f(a4.y) + bf2f(b4.y) - 1e9f * c4.y);
  o.z = f2bf(bf2f(a4.z) + bf2f(b4.z) - 1e9f * c4.z);
  o.w = f2bf(bf2f(a4.w) + bf2f(b4.w) - 1e9f * c4.w);
  ((ushort4*)ctx)[i] = o;
}

// ---- fused attention, key-split kz=2: ctxp[kz] = (mask? QK^T/8 : 0)@V
// over keys [kz*512, kz*512+512). qk layout [4096][2048]. 1024 blocks, 4/CU.
__global__ __launch_bounds__(256, 4) void attn_kernel(
    const unsigned short* __restrict__ qkb, const unsigned short* __restrict__ vT,
    const int* __restrict__ mask,
    unsigned short* __restrict__ ctxp0, unsigned short* __restrict__ ctxp1) {
  __shared__ __align__(16) unsigned short Qs[128 * 64];
  __shared__ __align__(16) unsigned short Ks[32 * 64];
  __shared__ __align__(16) unsigned short Vs[64 * 32];
  __shared__ __align__(16) unsigned short Ps[128 * 40];  // padded rows (80 B)
  const int tid = threadIdx.x, lane = tid & 63, w = tid >> 6;
  const int quad = lane >> 4, col = lane & 15;
  const int L = blockIdx.x + 8 * (blockIdx.y + 16 * blockIdx.z);  // 0..1023
  const int s_ = L >> 3;
  const int g = (L & 7) * 16 + (s_ >> 3);   // 0..127
  const int q0 = (s_ & 7) * 128;
  const int h = g & 15, bkz = g >> 4;
  const int b = bkz >> 1, kz = bkz & 1;
  const size_t qbase = ((size_t)(b * 1024 + q0)) * 2048 + h * 64;

#pragma unroll
  for (int t = 0; t < 4; ++t) {
    const int s = t * 256 + w * 64 + lane;
    const int m = s >> 3, c = (s & 7) ^ (m & 7);
    g2l16(qkb + qbase + (size_t)m * 2048 + c * 8, (void*)(Qs + s * 8));
  }
  __syncthreads();
  bf16x8 qf[2][2];
#pragma unroll
  for (int qt = 0; qt < 2; ++qt)
#pragma unroll
    for (int kf = 0; kf < 2; ++kf) {
      const int m = (w * 2 + qt) * 16 + col;
      const int c = (kf * 4 + quad) ^ (m & 7);
      qf[qt][kf] = *(const bf16x8*)(Qs + m * 64 + c * 8);
    }

  const f32x4 z4 = {0.f, 0.f, 0.f, 0.f};
  f32x4 oacc[2][4];
#pragma unroll
  for (int qt = 0; qt < 2; ++qt)
#pragma unroll
    for (int nt = 0; nt < 4; ++nt) oacc[qt][nt] = z4;

  const int* mrow = mask + b * 1024;
  const int kb0 = kz * 512;
  for (int kb = kb0; kb < kb0 + 512; kb += 32) {
    __syncthreads();
    {
      const int s = w * 64 + lane;
      const int key = s >> 3, ck = (s & 7) ^ (key & 7);
      g2l16(qkb + ((size_t)(b * 1024 + kb + key)) * 2048 + 1024 + h * 64 + ck * 8,
            (void*)(Ks + s * 8));
      const int d = s >> 2, cv = (s & 3) ^ (((d >> 2) ^ d) & 3);
      g2l16(vT + ((size_t)(h * 64 + d)) * 4096 + b * 1024 + kb + cv * 8,
            (void*)(Vs + s * 8));
    }
    __syncthreads();

    // S^T = K Q^T : C rows = key, cols = q
    f32x4 st[2][2];
#pragma unroll
    for (int qt = 0; qt < 2; ++qt)
#pragma unroll
      for (int kt = 0; kt < 2; ++kt) st[qt][kt] = z4;
#pragma unroll
    for (int kt = 0; kt < 2; ++kt)
#pragma unroll
      for (int kf = 0; kf < 2; ++kf) {
        const int key = kt * 16 + col;
        const int c = (kf * 4 + quad) ^ (key & 7);
        const bf16x8 kfrag = *(const bf16x8*)(Ks + key * 64 + c * 8);
#pragma unroll
        for (int qt = 0; qt < 2; ++qt)
          st[qt][kt] = __builtin_amdgcn_mfma_f32_16x16x32_bf16(
              kfrag, qf[qt][kf], st[qt][kt], 0, 0, 0);
      }

    // mask*scale then round-half-up pack; one b64 write per (qt,kt)
    const int4 mv0 = *(const int4*)(mrow + kb + quad * 4);
    const int4 mv1 = *(const int4*)(mrow + kb + 16 + quad * 4);
#pragma unroll
    for (int qt = 0; qt < 2; ++qt) {
      const int qrow = (w * 2 + qt) * 16 + col;
#pragma unroll
      for (int kt = 0; kt < 2; ++kt) {
        const int4 mv = kt ? mv1 : mv0;
        const f32x4 sv = st[qt][kt];
        const unsigned int u0 = fbits((mv.x ? 0.125f : 0.f) * sv[0]) + 0x8000u;
        const unsigned int u1 = fbits((mv.y ? 0.125f : 0.f) * sv[1]) + 0x8000u;
        const unsigned int u2 = fbits((mv.z ? 0.125f : 0.f) * sv[2]) + 0x8000u;
        const unsigned int u3 = fbits((mv.w ? 0.125f : 0.f) * sv[3]) + 0x8000u;
        uint2 pk;
        pk.x = (u0 >> 16) | (u1 & 0xFFFF0000u);
        pk.y = (u2 >> 16) | (u3 & 0xFFFF0000u);
        const int pp = kt * 2 + (quad >> 1);
        *(uint2*)(Ps + qrow * 40 + ((pp ^ (qrow & 3)) * 8 + (quad & 1) * 4)) = pk;
      }
    }
    // no barrier: wave w only touches its own q-rows

    // oacc += P @ V
#pragma unroll
    for (int qt = 0; qt < 2; ++qt) {
      const int qrow = (w * 2 + qt) * 16 + col;
      const bf16x8 pf = *(const bf16x8*)(Ps + qrow * 40 + (quad ^ (qrow & 3)) * 8);
#pragma unroll
      for (int nt = 0; nt < 4; ++nt) {
        const int vr = nt * 16 + col;
        const bf16x8 vf = *(const bf16x8*)(Vs + vr * 32 + ((quad ^ (((vr >> 2) ^ vr) & 3))) * 8);
        oacc[qt][nt] = __builtin_amdgcn_mfma_f32_16x16x32_bf16(pf, vf, oacc[qt][nt], 0, 0, 0);
      }
    }
  }

  unsigned short* P = kz ? ctxp1 : ctxp0;
#pragma unroll
  for (int qt = 0; qt < 2; ++qt)
#pragma unroll
    for (int nt = 0; nt < 4; ++nt) {
      const int d = nt * 16 + col;
#pragma unroll
      for (int r = 0; r < 4; ++r) {
        const int qq = q0 + (w * 2 + qt) * 16 + quad * 4 + r;
        P[((size_t)(b * 1024) + qq) * 1024 + h * 64 + d] = f2bf(oacc[qt][nt][r]);
      }
    }
}

extern "C" void kernel_launch(void* const* d_in, const int* in_sizes, int n_in,
                              void* d_out, int out_size, void* d_ws, size_t ws_size,
                              hipStream_t stream) {
  const float* x    = (const float*)d_in[0];
  const int*   mask = (const int*)d_in[1];
  const float* wq = (const float*)d_in[2];
  const float* bq = (const float*)d_in[3];
  const float* wk = (const float*)d_in[4];
  const float* bk = (const float*)d_in[5];
  const float* wv = (const float*)d_in[6];
  const float* bv = (const float*)d_in[7];
  const float* wo = (const float*)d_in[8];
  const float* bo = (const float*)d_in[9];
  const float* w1 = (const float*)d_in[10];
  const float* b1 = (const float*)d_in[11];
  const float* w2 = (const float*)d_in[12];
  const float* b2 = (const float*)d_in[13];
  const float* ln1a = (const float*)d_in[14];
  const float* ln1b = (const float*)d_in[15];
  const float* ln2a = (const float*)d_in[16];
  const float* ln2b = (const float*)d_in[17];
  float* out = (float*)d_out;
  char* W = (char*)d_ws;
  const size_t MB = 1u << 20;

  unsigned short* wqkvT = (unsigned short*)(W + 0 * MB);   // 6 MB [3072][1024]
  unsigned short* woT   = (unsigned short*)(W + 6 * MB);   // 2 MB
  unsigned short* w1T   = (unsigned short*)(W + 8 * MB);   // 8 MB
  unsigned short* w2T   = (unsigned short*)(W + 16 * MB);  // 8 MB
  float*          bqkv  = (float*)(W + 24 * MB);           // 12 KB
  float*          corr  = (float*)(W + 24 * MB + 65536);   // 16 KB
  unsigned short* xn    = (unsigned short*)(W + 25 * MB);  // 8 MB (xn / xn2)
  unsigned short* qkb   = (unsigned short*)(W + 33 * MB);  // 16 MB [4096][2048]
  unsigned short* vT    = (unsigned short*)(W + 49 * MB);  // 8 MB [1024][4096]
  unsigned short* ctxp0 = (unsigned short*)(W + 57 * MB);  // 8 MB
  unsigned short* ctxp1 = (unsigned short*)(W + 65 * MB);  // 8 MB
  unsigned short* ctx   = (unsigned short*)(W + 33 * MB);  // 8 MB (qkb dead)
  unsigned short* p0wo  = (unsigned short*)(W + 41 * MB);  // 8 MB (qkb dead)
  unsigned short* p1wo  = (unsigned short*)(W + 49 * MB);  // 8 MB (vT dead)
  unsigned short* x1    = (unsigned short*)(W + 73 * MB);  // 8 MB (fresh)
  unsigned short* xn2   = xn;                              // reuse
  unsigned short* hb    = (unsigned short*)(W + 33 * MB);  // 32 MB (33-65 dead)
  unsigned short* pf0   = (unsigned short*)(W + 0 * MB);   // 8 MB (wqkvT/woT dead)
  unsigned short* pf1   = (unsigned short*)(W + 8 * MB);   // 8 MB (w1T dead)
  unsigned short* pf2   = (unsigned short*)(W + 65 * MB);  // 8 MB (ctxp1 dead)
  unsigned short* pf3   = (unsigned short*)(W + 24 * MB);  // 8 MB (bqkv/corr/xn2 dead)

  // weights conversion + qkv bias + LN1 in one launch (independent blocks)
  wconv_ln_kernel<<<7169, 256, 0, stream>>>(wq, wk, wv, wo, w1, w2, bq, bk, bv,
                                            wqkvT, woT, w1T, w2T, bqkv,
                                            x, xn, ln1a, ln1b);
  // fused q|k|v GEMM: q/k row-major into qkb[4096][2048], v transposed
  // (+bias) straight into vT[1024][4096]. 768 blocks (3/CU), BK=64.
  mfma_gemm<128, 128, true, false, false, true, 12, 8>
      <<<dim3(24, 32), 256, 0, stream>>>(
      xn, wqkvT, bqkv, qkb, vT, nullptr, nullptr, 2048, 1024, 1024, 1024);
  // masked-V sums (raw; attn_combine applies -1e9)
  masksum_kernel<<<dim3(16, 4), 256, 0, stream>>>(vT, mask, corr);
  // attention, key-split kz=2: 1024 blocks (4/CU)
  attn_kernel<<<dim3(8, 16, 8), 256, 0, stream>>>(qkb, vT, mask, ctxp0, ctxp1);
  attn_combine_kernel<<<4096, 256, 0, stream>>>(ctxp0, ctxp1, corr, ctx);
  // wo-proj split-K z=2 (KH=512), bf16 partials
  mfma_gemm<128, 128, false, false, true, false, 8, 8>
      <<<dim3(8, 32, 2), 256, 0, stream>>>(
      ctx, woT, nullptr, p0wo, p1wo, nullptr, nullptr, 1024, 1024, 1024, 512);
  combine_ln_kernel<<<4096, 256, 0, stream>>>(p0wo, p1wo, x, bo, ln2a, ln2b, x1, xn2);
  // FFN1: 1024 blocks (4/CU), BK=64
  mfma_gemm<128, 128, true, true, false, false, 16, 8>
      <<<dim3(32, 32), 256, 0, stream>>>(
      xn2, w1T, b1, hb, nullptr, nullptr, nullptr, 4096, 1024, 1024, 1024);
  // FFN2 split-K z=4 (KH=1024), 1024 blocks (4/CU), bf16 partials
  mfma_gemm<128, 128, false, false, true, false, 8, 16>
      <<<dim3(8, 32, 4), 256, 0, stream>>>(
      hb, w2T, nullptr, pf0, pf1, pf2, pf3, 1024, 4096, 4096, 1024);
  combine_out_kernel<<<4096, 256, 0, stream>>>(pf0, pf1, pf2, pf3, x1, b2, out);
}

// Round 11
// 306.348 us; speedup vs baseline: 1.1412x; 1.1412x over previous
//
#include <hip/hip_runtime.h>
#include <hip/hip_bf16.h>
#include <math.h>

// ---------------------------------------------------------------------------
// EncoderBlock, bf16-MFMA, round 11: fix the round-10 masksum regression.
//  - masksum rewritten: 1024 blocks (one per hd row), coalesced ushort4/int4
//    reads along the contiguous vT row, wave+LDS reduce. (Round-10 version:
//    64 blocks, 8KB-strided per-lane serial streams -> 47us, 2.4% occupancy.)
//  - everything else identical to round 10 (VSPLIT qkv epilogue, fused
//    wconv+LN1, key-split attention, split-K GEMMs, region swizzle).
// ---------------------------------------------------------------------------

#define EPS 1e-5f

typedef __attribute__((ext_vector_type(8))) short bf16x8;
typedef __attribute__((ext_vector_type(4))) float f32x4;

typedef const __attribute__((address_space(1))) unsigned char glob_byte;
typedef __attribute__((address_space(3))) unsigned char lds_byte;

__device__ __forceinline__ void g2l16(const void* g, void* l) {
  __builtin_amdgcn_global_load_lds((glob_byte*)g, (lds_byte*)l, 16, 0, 0);
}

__device__ __forceinline__ unsigned short f2bf(float f) {
  union { float f; unsigned int u; } v; v.f = f;
  return (unsigned short)((v.u + 0x7FFFu + ((v.u >> 16) & 1u)) >> 16);
}
__device__ __forceinline__ float bf2f(unsigned short b) {
  union { unsigned int u; float f; } v; v.u = (unsigned int)b << 16;
  return v.f;
}
__device__ __forceinline__ unsigned int fbits(float f) {
  union { float f; unsigned int u; } v; v.f = f;
  return v.u;
}

// ---- weights fp32 [K][N] -> bf16 [N][K] (bid<3072); qkv bias (bid==3072);
// LN1 rows (bid>=3073): xn = LN(x) bf16.
__global__ __launch_bounds__(256) void wconv_ln_kernel(
    const float* __restrict__ wq, const float* __restrict__ wk,
    const float* __restrict__ wv, const float* __restrict__ wo,
    const float* __restrict__ w1, const float* __restrict__ w2,
    const float* __restrict__ bq, const float* __restrict__ bk,
    const float* __restrict__ bv,
    unsigned short* __restrict__ wqkvT, unsigned short* __restrict__ woT,
    unsigned short* __restrict__ w1T, unsigned short* __restrict__ w2T,
    float* __restrict__ bqkv,
    const float* __restrict__ x, unsigned short* __restrict__ xn,
    const float* __restrict__ ln1a, const float* __restrict__ ln1b) {
  __shared__ float tile[64][65];
  const int bid = blockIdx.x;
  const int t = threadIdx.x;
  if (bid >= 3073) {  // ---- LayerNorm (torch: ddof=1, /(std+eps))
    const int row = bid - 3073;
    const float4 v = ((const float4*)(x + (size_t)row * 1024))[t];
    float s  = v.x + v.y + v.z + v.w;
    float ss = v.x * v.x + v.y * v.y + v.z * v.z + v.w * v.w;
#pragma unroll
    for (int off = 32; off > 0; off >>= 1) {
      s  += __shfl_down(s, off, 64);
      ss += __shfl_down(ss, off, 64);
    }
    __shared__ float red[8];
    const int lane = t & 63, wv_ = t >> 6;
    if (lane == 0) { red[wv_] = s; red[4 + wv_] = ss; }
    __syncthreads();
    const float S  = red[0] + red[1] + red[2] + red[3];
    const float SS = red[4] + red[5] + red[6] + red[7];
    const float mean = S * (1.0f / 1024.0f);
    float var = (SS - 1024.0f * mean * mean) * (1.0f / 1023.0f);
    var = fmaxf(var, 0.0f);
    const float scl = ln1a[0] / (sqrtf(var) + EPS);
    const float b = ln1b[0];
    ushort4 o;
    o.x = f2bf((v.x - mean) * scl + b);
    o.y = f2bf((v.y - mean) * scl + b);
    o.z = f2bf((v.z - mean) * scl + b);
    o.w = f2bf((v.w - mean) * scl + b);
    ((ushort4*)(xn + (size_t)row * 1024))[t] = o;
    return;
  }
  if (bid == 3072) {  // ---- fused qkv bias
#pragma unroll
    for (int i = 0; i < 12; ++i) {
      const int n = i * 256 + t;
      bqkv[n] = n < 1024 ? bq[n] : (n < 2048 ? bk[n - 1024] : bv[n - 2048]);
    }
    return;
  }
  // ---- weight transpose+cast
  const float* src; unsigned short* dst; int K, N, tk, tn;
  if (bid < 1024) {
    const int m = bid >> 8, loc = bid & 255;
    src = m == 0 ? wq : m == 1 ? wk : m == 2 ? wv : wo;
    dst = m == 3 ? woT : (wqkvT + (size_t)m * 1024 * 1024);
    K = 1024; N = 1024; tk = loc >> 4; tn = loc & 15;
  } else if (bid < 2048) {
    const int loc = bid - 1024; src = w1; dst = w1T;
    K = 1024; N = 4096; tk = loc >> 6; tn = loc & 63;
  } else {
    const int loc = bid - 2048; src = w2; dst = w2T;
    K = 4096; N = 1024; tk = loc >> 4; tn = loc & 15;
  }
  const int lr = t >> 4, lc = (t & 15) * 4;
#pragma unroll
  for (int i = 0; i < 4; ++i) {
    const float4 v = *(const float4*)(src + (size_t)(tk * 64 + lr + 16 * i) * N + tn * 64 + lc);
    tile[lr + 16 * i][lc + 0] = v.x;
    tile[lr + 16 * i][lc + 1] = v.y;
    tile[lr + 16 * i][lc + 2] = v.z;
    tile[lr + 16 * i][lc + 3] = v.w;
  }
  __syncthreads();
  const int on = t >> 2, ok = (t & 3) * 16;
#pragma unroll
  for (int jj = 0; jj < 4; ++jj) {
    ushort4 o4;
    o4.x = f2bf(tile[ok + 4 * jj + 0][on]);
    o4.y = f2bf(tile[ok + 4 * jj + 1][on]);
    o4.z = f2bf(tile[ok + 4 * jj + 2][on]);
    o4.w = f2bf(tile[ok + 4 * jj + 3][on]);
    *(ushort4*)(dst + (size_t)(tn * 64 + on) * K + tk * 64 + ok + 4 * jj) = o4;
  }
}

// ---- bf16 MFMA GEMM, BK=64 (unchanged from round 10).
template <int TM, int TN, bool OUT_BF16, bool RELU, bool SPLITK, bool VSPLIT,
          int RX, int RY>
__global__ __launch_bounds__(256, 4) void mfma_gemm(
    const unsigned short* __restrict__ A, const unsigned short* __restrict__ Bt,
    const float* __restrict__ bias,
    void* __restrict__ C0, void* __restrict__ C1,
    void* __restrict__ C2, void* __restrict__ C3,
    int N, int lda, int ldb, int KH) {
  constexpr int WM = 2, WN = 2;
  constexpr int MSPAN = TM / WM, NSPAN = TN / WN;
  constexpr int MI = MSPAN / 16, NJ = NSPAN / 16;
  __shared__ __align__(16) unsigned short As[TM * 64];
  __shared__ __align__(16) unsigned short Bs[TN * 64];
  const int tid = threadIdx.x, lane = tid & 63;
  const int w = tid >> 6;
  const int quad = lane >> 4, col = lane & 15;
  const int wm = w % WM, wn = w / WM;

  int bx = blockIdx.x, by = blockIdx.y, bz = blockIdx.z;
  {
    const int gx = gridDim.x, gy = gridDim.y;
    const int L = bx + gx * (by + gy * bz);
    const int r = L & 7, s = L >> 3;
    const int nrx = gx / RX, nry = gy / RY;
    const int rx = r % nrx, rem = r / nrx;
    const int ry = rem % nry, rz = rem / nry;
    bx = rx * RX + s % RX;
    by = ry * RY + (s / RX) % RY;
    bz = rz;
  }
  const int m0 = by * TM, n0 = bx * TN;
  const int koff = SPLITK ? bz * KH : 0;

  f32x4 acc[MI][NJ];
  const f32x4 z4 = {0.f, 0.f, 0.f, 0.f};
#pragma unroll
  for (int i = 0; i < MI; ++i)
#pragma unroll
    for (int j = 0; j < NJ; ++j) acc[i][j] = z4;

  for (int k0 = 0; k0 < KH; k0 += 64) {
    __syncthreads();
#pragma unroll
    for (int t = 0; t < TM / 32; ++t) {
      const int s = t * 256 + tid;
      const int r = s >> 3, c = (s & 7) ^ (r & 7);
      g2l16(A + (size_t)(m0 + r) * lda + koff + k0 + c * 8, (void*)(As + s * 8));
    }
#pragma unroll
    for (int t = 0; t < TN / 32; ++t) {
      const int s = t * 256 + tid;
      const int r = s >> 3, c = (s & 7) ^ (r & 7);
      g2l16(Bt + (size_t)(n0 + r) * ldb + koff + k0 + c * 8, (void*)(Bs + s * 8));
    }
    __syncthreads();
#pragma unroll
    for (int h = 0; h < 2; ++h) {
      bf16x8 af[MI], bfr[NJ];
#pragma unroll
      for (int i = 0; i < MI; ++i) {
        const int rr = wm * MSPAN + i * 16 + col;
        af[i] = *(const bf16x8*)(As + rr * 64 + (((h << 2) | quad) ^ (rr & 7)) * 8);
      }
#pragma unroll
      for (int j = 0; j < NJ; ++j) {
        const int rr = wn * NSPAN + j * 16 + col;
        bfr[j] = *(const bf16x8*)(Bs + rr * 64 + (((h << 2) | quad) ^ (rr & 7)) * 8);
      }
#pragma unroll
      for (int i = 0; i < MI; ++i)
#pragma unroll
        for (int j = 0; j < NJ; ++j)
          acc[i][j] = __builtin_amdgcn_mfma_f32_16x16x32_bf16(af[i], bfr[j], acc[i][j], 0, 0, 0);
    }
  }
#pragma unroll
  for (int i = 0; i < MI; ++i) {
    const int mrow = m0 + wm * MSPAN + i * 16 + quad * 4;
#pragma unroll
    for (int j = 0; j < NJ; ++j) {
      const int n = n0 + wn * NSPAN + j * 16 + col;
      const float bn = SPLITK ? 0.f : bias[n];
      if (VSPLIT && n0 >= 2048) {
        // v-tile: transposed store, 4 consecutive tokens -> one ushort4
        ushort4 o4;
        o4.x = f2bf(acc[i][j][0] + bn);
        o4.y = f2bf(acc[i][j][1] + bn);
        o4.z = f2bf(acc[i][j][2] + bn);
        o4.w = f2bf(acc[i][j][3] + bn);
        *(ushort4*)((unsigned short*)C1 + (size_t)(n - 2048) * 4096 + mrow) = o4;
        continue;
      }
#pragma unroll
      for (int r = 0; r < 4; ++r) {
        const int m = mrow + r;
        if (SPLITK) {
          unsigned short* P = bz == 0 ? (unsigned short*)C0
                            : bz == 1 ? (unsigned short*)C1
                            : bz == 2 ? (unsigned short*)C2
                                      : (unsigned short*)C3;
          P[(size_t)m * N + n] = f2bf(acc[i][j][r]);
        } else {
          float v = acc[i][j][r] + bn;
          if (RELU) v = fmaxf(v, 0.f);
          if (OUT_BF16) ((unsigned short*)C0)[(size_t)m * N + n] = f2bf(v);
          else          ((float*)C0)[(size_t)m * N + n] = v;
        }
      }
    }
  }
}

// ---- corr[b*1024+hd] = sum_{tok: mask==0} V[tok][hd]  (raw; combine
// applies -1e9). One block per hd row of vT: fully coalesced ushort4 reads.
__global__ __launch_bounds__(256) void masksum_kernel(
    const unsigned short* __restrict__ vT, const int* __restrict__ mask,
    float* __restrict__ corr) {
  const int hd = blockIdx.x, t = threadIdx.x;
  const int lane = t & 63, w = t >> 6;
  float sb[4];
#pragma unroll
  for (int b = 0; b < 4; ++b) {
    const ushort4 v4 = *(const ushort4*)(vT + (size_t)hd * 4096 + b * 1024 + t * 4);
    const int4 m4 = *(const int4*)(mask + b * 1024 + t * 4);
    float s = 0.f;
    if (m4.x == 0) s += bf2f(v4.x);
    if (m4.y == 0) s += bf2f(v4.y);
    if (m4.z == 0) s += bf2f(v4.z);
    if (m4.w == 0) s += bf2f(v4.w);
#pragma unroll
    for (int off = 32; off > 0; off >>= 1) s += __shfl_down(s, off, 64);
    sb[b] = s;
  }
  __shared__ float red[4][4];
  if (lane == 0) {
    red[w][0] = sb[0]; red[w][1] = sb[1]; red[w][2] = sb[2]; red[w][3] = sb[3];
  }
  __syncthreads();
  if (t < 4)
    corr[t * 1024 + hd] = red[0][t] + red[1][t] + red[2][t] + red[3][t];
}

// ---- combine wo partials (bf16) + x + bo -> x1 (bf16) ; xn2 = LN2.
__global__ __launch_bounds__(256) void combine_ln_kernel(
    const unsigned short* __restrict__ p0, const unsigned short* __restrict__ p1,
    const float* __restrict__ x, const float* __restrict__ bo,
    const float* __restrict__ alpha, const float* __restrict__ beta,
    unsigned short* __restrict__ x1, unsigned short* __restrict__ xn2) {
  const int row = blockIdx.x, t = threadIdx.x;
  const size_t i = (size_t)row * 256 + t;
  const ushort4 a4 = ((const ushort4*)p0)[i];
  const ushort4 b4 = ((const ushort4*)p1)[i];
  const float4 x4 = ((const float4*)x)[i];
  const float4 o4 = ((const float4*)bo)[t];
  float4 v;
  v.x = bf2f(a4.x) + bf2f(b4.x) + x4.x + o4.x;
  v.y = bf2f(a4.y) + bf2f(b4.y) + x4.y + o4.y;
  v.z = bf2f(a4.z) + bf2f(b4.z) + x4.z + o4.z;
  v.w = bf2f(a4.w) + bf2f(b4.w) + x4.w + o4.w;
  ushort4 xb;
  xb.x = f2bf(v.x); xb.y = f2bf(v.y); xb.z = f2bf(v.z); xb.w = f2bf(v.w);
  ((ushort4*)x1)[i] = xb;
  float s  = v.x + v.y + v.z + v.w;
  float ss = v.x * v.x + v.y * v.y + v.z * v.z + v.w * v.w;
#pragma unroll
  for (int off = 32; off > 0; off >>= 1) {
    s  += __shfl_down(s, off, 64);
    ss += __shfl_down(ss, off, 64);
  }
  __shared__ float red[8];
  const int lane = t & 63, wv_ = t >> 6;
  if (lane == 0) { red[wv_] = s; red[4 + wv_] = ss; }
  __syncthreads();
  const float S  = red[0] + red[1] + red[2] + red[3];
  const float SS = red[4] + red[5] + red[6] + red[7];
  const float mean = S * (1.0f / 1024.0f);
  float var = (SS - 1024.0f * mean * mean) * (1.0f / 1023.0f);
  var = fmaxf(var, 0.0f);
  const float scl = alpha[0] / (sqrtf(var) + EPS);
  const float bb = beta[0];
  ushort4 o;
  o.x = f2bf((v.x - mean) * scl + bb);
  o.y = f2bf((v.y - mean) * scl + bb);
  o.z = f2bf((v.z - mean) * scl + bb);
  o.w = f2bf((v.w - mean) * scl + bb);
  ((ushort4*)xn2)[i] = o;
}

// ---- combine ffn2 partials (4x bf16) + x1 (bf16) + b2 -> out fp32.
__global__ __launch_bounds__(256) void combine_out_kernel(
    const unsigned short* __restrict__ pf0, const unsigned short* __restrict__ pf1,
    const unsigned short* __restrict__ pf2, const unsigned short* __restrict__ pf3,
    const unsigned short* __restrict__ x1, const float* __restrict__ b2,
    float* __restrict__ out) {
  const int t = threadIdx.x;
  const size_t i = (size_t)blockIdx.x * 256 + t;
  const ushort4 a4 = ((const ushort4*)pf0)[i];
  const ushort4 b4 = ((const ushort4*)pf1)[i];
  const ushort4 c4 = ((const ushort4*)pf2)[i];
  const ushort4 d4 = ((const ushort4*)pf3)[i];
  const ushort4 e4 = ((const ushort4*)x1)[i];
  const float4 f4 = ((const float4*)b2)[t];
  float4 v;
  v.x = bf2f(a4.x) + bf2f(b4.x) + bf2f(c4.x) + bf2f(d4.x) + bf2f(e4.x) + f4.x;
  v.y = bf2f(a4.y) + bf2f(b4.y) + bf2f(c4.y) + bf2f(d4.y) + bf2f(e4.y) + f4.y;
  v.z = bf2f(a4.z) + bf2f(b4.z) + bf2f(c4.z) + bf2f(d4.z) + bf2f(e4.z) + f4.z;
  v.w = bf2f(a4.w) + bf2f(b4.w) + bf2f(c4.w) + bf2f(d4.w) + bf2f(e4.w) + f4.w;
  ((float4*)out)[i] = v;
}

// ---- combine attention key-halves + corr -> ctx (bf16)
__global__ __launch_bounds__(256) void attn_combine_kernel(
    const unsigned short* __restrict__ p0, const unsigned short* __restrict__ p1,
    const float* __restrict__ corr, unsigned short* __restrict__ ctx) {
  const int row = blockIdx.x, t = threadIdx.x;
  const size_t i = (size_t)row * 256 + t;
  const ushort4 a4 = ((const ushort4*)p0)[i];
  const ushort4 b4 = ((const ushort4*)p1)[i];
  const float4 c4 = ((const float4*)(corr + (row >> 10) * 1024))[t];
  ushort4 o;
  o.x = f2bf(bf2f(a4.x) + bf2f(b4.x) - 1e9f * c4.x);
  o.y = f2bf(bf2f(a4.y) + bf2f(b4.y) - 1e9f * c4.y);
  o.z = f2bf(bf2f(a4.z) + bf2f(b4.z) - 1e9f * c4.z);
  o.w = f2bf(bf2f(a4.w) + bf2f(b4.w) - 1e9f * c4.w);
  ((ushort4*)ctx)[i] = o;
}

// ---- fused attention, key-split kz=2: ctxp[kz] = (mask? QK^T/8 : 0)@V
// over keys [kz*512, kz*512+512). qk layout [4096][2048]. 1024 blocks, 4/CU.
__global__ __launch_bounds__(256, 4) void attn_kernel(
    const unsigned short* __restrict__ qkb, const unsigned short* __restrict__ vT,
    const int* __restrict__ mask,
    unsigned short* __restrict__ ctxp0, unsigned short* __restrict__ ctxp1) {
  __shared__ __align__(16) unsigned short Qs[128 * 64];
  __shared__ __align__(16) unsigned short Ks[32 * 64];
  __shared__ __align__(16) unsigned short Vs[64 * 32];
  __shared__ __align__(16) unsigned short Ps[128 * 40];  // padded rows (80 B)
  const int tid = threadIdx.x, lane = tid & 63, w = tid >> 6;
  const int quad = lane >> 4, col = lane & 15;
  const int L = blockIdx.x + 8 * (blockIdx.y + 16 * blockIdx.z);  // 0..1023
  const int s_ = L >> 3;
  const int g = (L & 7) * 16 + (s_ >> 3);   // 0..127
  const int q0 = (s_ & 7) * 128;
  const int h = g & 15, bkz = g >> 4;
  const int b = bkz >> 1, kz = bkz & 1;
  const size_t qbase = ((size_t)(b * 1024 + q0)) * 2048 + h * 64;

#pragma unroll
  for (int t = 0; t < 4; ++t) {
    const int s = t * 256 + w * 64 + lane;
    const int m = s >> 3, c = (s & 7) ^ (m & 7);
    g2l16(qkb + qbase + (size_t)m * 2048 + c * 8, (void*)(Qs + s * 8));
  }
  __syncthreads();
  bf16x8 qf[2][2];
#pragma unroll
  for (int qt = 0; qt < 2; ++qt)
#pragma unroll
    for (int kf = 0; kf < 2; ++kf) {
      const int m = (w * 2 + qt) * 16 + col;
      const int c = (kf * 4 + quad) ^ (m & 7);
      qf[qt][kf] = *(const bf16x8*)(Qs + m * 64 + c * 8);
    }

  const f32x4 z4 = {0.f, 0.f, 0.f, 0.f};
  f32x4 oacc[2][4];
#pragma unroll
  for (int qt = 0; qt < 2; ++qt)
#pragma unroll
    for (int nt = 0; nt < 4; ++nt) oacc[qt][nt] = z4;

  const int* mrow = mask + b * 1024;
  const int kb0 = kz * 512;
  for (int kb = kb0; kb < kb0 + 512; kb += 32) {
    __syncthreads();
    {
      const int s = w * 64 + lane;
      const int key = s >> 3, ck = (s & 7) ^ (key & 7);
      g2l16(qkb + ((size_t)(b * 1024 + kb + key)) * 2048 + 1024 + h * 64 + ck * 8,
            (void*)(Ks + s * 8));
      const int d = s >> 2, cv = (s & 3) ^ (((d >> 2) ^ d) & 3);
      g2l16(vT + ((size_t)(h * 64 + d)) * 4096 + b * 1024 + kb + cv * 8,
            (void*)(Vs + s * 8));
    }
    __syncthreads();

    // S^T = K Q^T : C rows = key, cols = q
    f32x4 st[2][2];
#pragma unroll
    for (int qt = 0; qt < 2; ++qt)
#pragma unroll
      for (int kt = 0; kt < 2; ++kt) st[qt][kt] = z4;
#pragma unroll
    for (int kt = 0; kt < 2; ++kt)
#pragma unroll
      for (int kf = 0; kf < 2; ++kf) {
        const int key = kt * 16 + col;
        const int c = (kf * 4 + quad) ^ (key & 7);
        const bf16x8 kfrag = *(const bf16x8*)(Ks + key * 64 + c * 8);
#pragma unroll
        for (int qt = 0; qt < 2; ++qt)
          st[qt][kt] = __builtin_amdgcn_mfma_f32_16x16x32_bf16(
              kfrag, qf[qt][kf], st[qt][kt], 0, 0, 0);
      }

    // mask*scale then round-half-up pack; one b64 write per (qt,kt)
    const int4 mv0 = *(const int4*)(mrow + kb + quad * 4);
    const int4 mv1 = *(const int4*)(mrow + kb + 16 + quad * 4);
#pragma unroll
    for (int qt = 0; qt < 2; ++qt) {
      const int qrow = (w * 2 + qt) * 16 + col;
#pragma unroll
      for (int kt = 0; kt < 2; ++kt) {
        const int4 mv = kt ? mv1 : mv0;
        const f32x4 sv = st[qt][kt];
        const unsigned int u0 = fbits((mv.x ? 0.125f : 0.f) * sv[0]) + 0x8000u;
        const unsigned int u1 = fbits((mv.y ? 0.125f : 0.f) * sv[1]) + 0x8000u;
        const unsigned int u2 = fbits((mv.z ? 0.125f : 0.f) * sv[2]) + 0x8000u;
        const unsigned int u3 = fbits((mv.w ? 0.125f : 0.f) * sv[3]) + 0x8000u;
        uint2 pk;
        pk.x = (u0 >> 16) | (u1 & 0xFFFF0000u);
        pk.y = (u2 >> 16) | (u3 & 0xFFFF0000u);
        const int pp = kt * 2 + (quad >> 1);
        *(uint2*)(Ps + qrow * 40 + ((pp ^ (qrow & 3)) * 8 + (quad & 1) * 4)) = pk;
      }
    }
    // no barrier: wave w only touches its own q-rows

    // oacc += P @ V
#pragma unroll
    for (int qt = 0; qt < 2; ++qt) {
      const int qrow = (w * 2 + qt) * 16 + col;
      const bf16x8 pf = *(const bf16x8*)(Ps + qrow * 40 + (quad ^ (qrow & 3)) * 8);
#pragma unroll
      for (int nt = 0; nt < 4; ++nt) {
        const int vr = nt * 16 + col;
        const bf16x8 vf = *(const bf16x8*)(Vs + vr * 32 + ((quad ^ (((vr >> 2) ^ vr) & 3))) * 8);
        oacc[qt][nt] = __builtin_amdgcn_mfma_f32_16x16x32_bf16(pf, vf, oacc[qt][nt], 0, 0, 0);
      }
    }
  }

  unsigned short* P = kz ? ctxp1 : ctxp0;
#pragma unroll
  for (int qt = 0; qt < 2; ++qt)
#pragma unroll
    for (int nt = 0; nt < 4; ++nt) {
      const int d = nt * 16 + col;
#pragma unroll
      for (int r = 0; r < 4; ++r) {
        const int qq = q0 + (w * 2 + qt) * 16 + quad * 4 + r;
        P[((size_t)(b * 1024) + qq) * 1024 + h * 64 + d] = f2bf(oacc[qt][nt][r]);
      }
    }
}

extern "C" void kernel_launch(void* const* d_in, const int* in_sizes, int n_in,
                              void* d_out, int out_size, void* d_ws, size_t ws_size,
                              hipStream_t stream) {
  const float* x    = (const float*)d_in[0];
  const int*   mask = (const int*)d_in[1];
  const float* wq = (const float*)d_in[2];
  const float* bq = (const float*)d_in[3];
  const float* wk = (const float*)d_in[4];
  const float* bk = (const float*)d_in[5];
  const float* wv = (const float*)d_in[6];
  const float* bv = (const float*)d_in[7];
  const float* wo = (const float*)d_in[8];
  const float* bo = (const float*)d_in[9];
  const float* w1 = (const float*)d_in[10];
  const float* b1 = (const float*)d_in[11];
  const float* w2 = (const float*)d_in[12];
  const float* b2 = (const float*)d_in[13];
  const float* ln1a = (const float*)d_in[14];
  const float* ln1b = (const float*)d_in[15];
  const float* ln2a = (const float*)d_in[16];
  const float* ln2b = (const float*)d_in[17];
  float* out = (float*)d_out;
  char* W = (char*)d_ws;
  const size_t MB = 1u << 20;

  unsigned short* wqkvT = (unsigned short*)(W + 0 * MB);   // 6 MB [3072][1024]
  unsigned short* woT   = (unsigned short*)(W + 6 * MB);   // 2 MB
  unsigned short* w1T   = (unsigned short*)(W + 8 * MB);   // 8 MB
  unsigned short* w2T   = (unsigned short*)(W + 16 * MB);  // 8 MB
  float*          bqkv  = (float*)(W + 24 * MB);           // 12 KB
  float*          corr  = (float*)(W + 24 * MB + 65536);   // 16 KB
  unsigned short* xn    = (unsigned short*)(W + 25 * MB);  // 8 MB (xn / xn2)
  unsigned short* qkb   = (unsigned short*)(W + 33 * MB);  // 16 MB [4096][2048]
  unsigned short* vT    = (unsigned short*)(W + 49 * MB);  // 8 MB [1024][4096]
  unsigned short* ctxp0 = (unsigned short*)(W + 57 * MB);  // 8 MB
  unsigned short* ctxp1 = (unsigned short*)(W + 65 * MB);  // 8 MB
  unsigned short* ctx   = (unsigned short*)(W + 33 * MB);  // 8 MB (qkb dead)
  unsigned short* p0wo  = (unsigned short*)(W + 41 * MB);  // 8 MB (qkb dead)
  unsigned short* p1wo  = (unsigned short*)(W + 49 * MB);  // 8 MB (vT dead)
  unsigned short* x1    = (unsigned short*)(W + 73 * MB);  // 8 MB (fresh)
  unsigned short* xn2   = xn;                              // reuse
  unsigned short* hb    = (unsigned short*)(W + 33 * MB);  // 32 MB (33-65 dead)
  unsigned short* pf0   = (unsigned short*)(W + 0 * MB);   // 8 MB (wqkvT/woT dead)
  unsigned short* pf1   = (unsigned short*)(W + 8 * MB);   // 8 MB (w1T dead)
  unsigned short* pf2   = (unsigned short*)(W + 65 * MB);  // 8 MB (ctxp1 dead)
  unsigned short* pf3   = (unsigned short*)(W + 24 * MB);  // 8 MB (bqkv/corr/xn2 dead)

  // weights conversion + qkv bias + LN1 in one launch (independent blocks)
  wconv_ln_kernel<<<7169, 256, 0, stream>>>(wq, wk, wv, wo, w1, w2, bq, bk, bv,
                                            wqkvT, woT, w1T, w2T, bqkv,
                                            x, xn, ln1a, ln1b);
  // fused q|k|v GEMM: q/k row-major into qkb[4096][2048], v transposed
  // (+bias) straight into vT[1024][4096]. 768 blocks (3/CU), BK=64.
  mfma_gemm<128, 128, true, false, false, true, 12, 8>
      <<<dim3(24, 32), 256, 0, stream>>>(
      xn, wqkvT, bqkv, qkb, vT, nullptr, nullptr, 2048, 1024, 1024, 1024);
  // masked-V sums: 1024 blocks, coalesced (raw; attn_combine applies -1e9)
  masksum_kernel<<<1024, 256, 0, stream>>>(vT, mask, corr);
  // attention, key-split kz=2: 1024 blocks (4/CU)
  attn_kernel<<<dim3(8, 16, 8), 256, 0, stream>>>(qkb, vT, mask, ctxp0, ctxp1);
  attn_combine_kernel<<<4096, 256, 0, stream>>>(ctxp0, ctxp1, corr, ctx);
  // wo-proj split-K z=2 (KH=512), bf16 partials
  mfma_gemm<128, 128, false, false, true, false, 8, 8>
      <<<dim3(8, 32, 2), 256, 0, stream>>>(
      ctx, woT, nullptr, p0wo, p1wo, nullptr, nullptr, 1024, 1024, 1024, 512);
  combine_ln_kernel<<<4096, 256, 0, stream>>>(p0wo, p1wo, x, bo, ln2a, ln2b, x1, xn2);
  // FFN1: 1024 blocks (4/CU), BK=64
  mfma_gemm<128, 128, true, true, false, false, 16, 8>
      <<<dim3(32, 32), 256, 0, stream>>>(
      xn2, w1T, b1, hb, nullptr, nullptr, nullptr, 4096, 1024, 1024, 1024);
  // FFN2 split-K z=4 (KH=1024), 1024 blocks (4/CU), bf16 partials
  mfma_gemm<128, 128, false, false, true, false, 8, 16>
      <<<dim3(8, 32, 4), 256, 0, stream>>>(
      hb, w2T, nullptr, pf0, pf1, pf2, pf3, 1024, 4096, 4096, 1024);
  combine_out_kernel<<<4096, 256, 0, stream>>>(pf0, pf1, pf2, pf3, x1, b2, out);
}

// Round 12
// 300.194 us; speedup vs baseline: 1.1646x; 1.0205x over previous
//
#include <hip/hip_runtime.h>
#include <hip/hip_bf16.h>
#include <math.h>

// ---------------------------------------------------------------------------
// EncoderBlock, round 12: MX-fp8 FFN.
//  - ffn1/ffn2 on mfma_scale_f32_16x16x128_f8f6f4 (unit E8M0 scales = plain
//    fp8 at the 2x MX rate). BK=128 fp8 rows = 128B = same LDS/staging math
//    as the bf16 BK=64 tile, 2x FLOP per barrier.
//  - V-path (qkv GEMM, attention, wo-proj) stays bf16: the -1e9*maskedV
//    error amplification forbids fp8 there; FFN values are O(1) -> safe.
//  - w1/w2 converted to fp8 in wconv; xn2 emitted fp8 by combine_ln;
//    hb emitted fp8 by ffn1 epilogue. Everything else = round 11.
// ---------------------------------------------------------------------------

#define EPS 1e-5f

typedef __attribute__((ext_vector_type(8))) short bf16x8;
typedef __attribute__((ext_vector_type(4))) float f32x4;
typedef __attribute__((ext_vector_type(8))) int i32x8;
typedef __attribute__((ext_vector_type(4))) int i32x4;

typedef const __attribute__((address_space(1))) unsigned char glob_byte;
typedef __attribute__((address_space(3))) unsigned char lds_byte;

__device__ __forceinline__ void g2l16(const void* g, void* l) {
  __builtin_amdgcn_global_load_lds((glob_byte*)g, (lds_byte*)l, 16, 0, 0);
}

__device__ __forceinline__ unsigned short f2bf(float f) {
  union { float f; unsigned int u; } v; v.f = f;
  return (unsigned short)((v.u + 0x7FFFu + ((v.u >> 16) & 1u)) >> 16);
}
__device__ __forceinline__ float bf2f(unsigned short b) {
  union { unsigned int u; float f; } v; v.u = (unsigned int)b << 16;
  return v.f;
}
__device__ __forceinline__ unsigned int fbits(float f) {
  union { float f; unsigned int u; } v; v.f = f;
  return v.u;
}
// pack 4 fp32 -> 4 fp8 e4m3 bytes
__device__ __forceinline__ unsigned int pk_fp8x4(float a, float b, float c, float d) {
  unsigned int p = 0;
  p = __builtin_amdgcn_cvt_pk_fp8_f32(a, b, p, false);
  p = __builtin_amdgcn_cvt_pk_fp8_f32(c, d, p, true);
  return p;
}

// ---- weights: wq..wo -> bf16 [N][K]; w1/w2 -> fp8 [N][K]; qkv bias; LN1.
__global__ __launch_bounds__(256) void wconv_ln_kernel(
    const float* __restrict__ wq, const float* __restrict__ wk,
    const float* __restrict__ wv, const float* __restrict__ wo,
    const float* __restrict__ w1, const float* __restrict__ w2,
    const float* __restrict__ bq, const float* __restrict__ bk,
    const float* __restrict__ bv,
    unsigned short* __restrict__ wqkvT, unsigned short* __restrict__ woT,
    unsigned char* __restrict__ w1F8, unsigned char* __restrict__ w2F8,
    float* __restrict__ bqkv,
    const float* __restrict__ x, unsigned short* __restrict__ xn,
    const float* __restrict__ ln1a, const float* __restrict__ ln1b) {
  __shared__ float tile[64][65];
  const int bid = blockIdx.x;
  const int t = threadIdx.x;
  if (bid >= 3073) {  // ---- LayerNorm (torch: ddof=1, /(std+eps))
    const int row = bid - 3073;
    const float4 v = ((const float4*)(x + (size_t)row * 1024))[t];
    float s  = v.x + v.y + v.z + v.w;
    float ss = v.x * v.x + v.y * v.y + v.z * v.z + v.w * v.w;
#pragma unroll
    for (int off = 32; off > 0; off >>= 1) {
      s  += __shfl_down(s, off, 64);
      ss += __shfl_down(ss, off, 64);
    }
    __shared__ float red[8];
    const int lane = t & 63, wv_ = t >> 6;
    if (lane == 0) { red[wv_] = s; red[4 + wv_] = ss; }
    __syncthreads();
    const float S  = red[0] + red[1] + red[2] + red[3];
    const float SS = red[4] + red[5] + red[6] + red[7];
    const float mean = S * (1.0f / 1024.0f);
    float var = (SS - 1024.0f * mean * mean) * (1.0f / 1023.0f);
    var = fmaxf(var, 0.0f);
    const float scl = ln1a[0] / (sqrtf(var) + EPS);
    const float b = ln1b[0];
    ushort4 o;
    o.x = f2bf((v.x - mean) * scl + b);
    o.y = f2bf((v.y - mean) * scl + b);
    o.z = f2bf((v.z - mean) * scl + b);
    o.w = f2bf((v.w - mean) * scl + b);
    ((ushort4*)(xn + (size_t)row * 1024))[t] = o;
    return;
  }
  if (bid == 3072) {  // ---- fused qkv bias
#pragma unroll
    for (int i = 0; i < 12; ++i) {
      const int n = i * 256 + t;
      bqkv[n] = n < 1024 ? bq[n] : (n < 2048 ? bk[n - 1024] : bv[n - 2048]);
    }
    return;
  }
  // ---- weight transpose+cast
  const float* src; int K, N, tk, tn;
  unsigned short* dst16 = nullptr; unsigned char* dst8 = nullptr;
  if (bid < 1024) {
    const int m = bid >> 8, loc = bid & 255;
    src = m == 0 ? wq : m == 1 ? wk : m == 2 ? wv : wo;
    dst16 = m == 3 ? woT : (wqkvT + (size_t)m * 1024 * 1024);
    K = 1024; N = 1024; tk = loc >> 4; tn = loc & 15;
  } else if (bid < 2048) {
    const int loc = bid - 1024; src = w1; dst8 = w1F8;
    K = 1024; N = 4096; tk = loc >> 6; tn = loc & 63;
  } else {
    const int loc = bid - 2048; src = w2; dst8 = w2F8;
    K = 4096; N = 1024; tk = loc >> 4; tn = loc & 15;
  }
  const int lr = t >> 4, lc = (t & 15) * 4;
#pragma unroll
  for (int i = 0; i < 4; ++i) {
    const float4 v = *(const float4*)(src + (size_t)(tk * 64 + lr + 16 * i) * N + tn * 64 + lc);
    tile[lr + 16 * i][lc + 0] = v.x;
    tile[lr + 16 * i][lc + 1] = v.y;
    tile[lr + 16 * i][lc + 2] = v.z;
    tile[lr + 16 * i][lc + 3] = v.w;
  }
  __syncthreads();
  const int on = t >> 2, ok = (t & 3) * 16;
#pragma unroll
  for (int jj = 0; jj < 4; ++jj) {
    if (dst8) {
      const unsigned int p = pk_fp8x4(tile[ok + 4 * jj + 0][on], tile[ok + 4 * jj + 1][on],
                                      tile[ok + 4 * jj + 2][on], tile[ok + 4 * jj + 3][on]);
      *(unsigned int*)(dst8 + (size_t)(tn * 64 + on) * K + tk * 64 + ok + 4 * jj) = p;
    } else {
      ushort4 o4;
      o4.x = f2bf(tile[ok + 4 * jj + 0][on]);
      o4.y = f2bf(tile[ok + 4 * jj + 1][on]);
      o4.z = f2bf(tile[ok + 4 * jj + 2][on]);
      o4.w = f2bf(tile[ok + 4 * jj + 3][on]);
      *(ushort4*)(dst16 + (size_t)(tn * 64 + on) * K + tk * 64 + ok + 4 * jj) = o4;
    }
  }
}

// ---- bf16 MFMA GEMM, BK=64 (unchanged from round 11).
template <int TM, int TN, bool OUT_BF16, bool RELU, bool SPLITK, bool VSPLIT,
          int RX, int RY>
__global__ __launch_bounds__(256, 4) void mfma_gemm(
    const unsigned short* __restrict__ A, const unsigned short* __restrict__ Bt,
    const float* __restrict__ bias,
    void* __restrict__ C0, void* __restrict__ C1,
    void* __restrict__ C2, void* __restrict__ C3,
    int N, int lda, int ldb, int KH) {
  constexpr int WM = 2, WN = 2;
  constexpr int MSPAN = TM / WM, NSPAN = TN / WN;
  constexpr int MI = MSPAN / 16, NJ = NSPAN / 16;
  __shared__ __align__(16) unsigned short As[TM * 64];
  __shared__ __align__(16) unsigned short Bs[TN * 64];
  const int tid = threadIdx.x, lane = tid & 63;
  const int w = tid >> 6;
  const int quad = lane >> 4, col = lane & 15;
  const int wm = w % WM, wn = w / WM;

  int bx = blockIdx.x, by = blockIdx.y, bz = blockIdx.z;
  {
    const int gx = gridDim.x, gy = gridDim.y;
    const int L = bx + gx * (by + gy * bz);
    const int r = L & 7, s = L >> 3;
    const int nrx = gx / RX, nry = gy / RY;
    const int rx = r % nrx, rem = r / nrx;
    const int ry = rem % nry, rz = rem / nry;
    bx = rx * RX + s % RX;
    by = ry * RY + (s / RX) % RY;
    bz = rz;
  }
  const int m0 = by * TM, n0 = bx * TN;
  const int koff = SPLITK ? bz * KH : 0;

  f32x4 acc[MI][NJ];
  const f32x4 z4 = {0.f, 0.f, 0.f, 0.f};
#pragma unroll
  for (int i = 0; i < MI; ++i)
#pragma unroll
    for (int j = 0; j < NJ; ++j) acc[i][j] = z4;

  for (int k0 = 0; k0 < KH; k0 += 64) {
    __syncthreads();
#pragma unroll
    for (int t = 0; t < TM / 32; ++t) {
      const int s = t * 256 + tid;
      const int r = s >> 3, c = (s & 7) ^ (r & 7);
      g2l16(A + (size_t)(m0 + r) * lda + koff + k0 + c * 8, (void*)(As + s * 8));
    }
#pragma unroll
    for (int t = 0; t < TN / 32; ++t) {
      const int s = t * 256 + tid;
      const int r = s >> 3, c = (s & 7) ^ (r & 7);
      g2l16(Bt + (size_t)(n0 + r) * ldb + koff + k0 + c * 8, (void*)(Bs + s * 8));
    }
    __syncthreads();
#pragma unroll
    for (int h = 0; h < 2; ++h) {
      bf16x8 af[MI], bfr[NJ];
#pragma unroll
      for (int i = 0; i < MI; ++i) {
        const int rr = wm * MSPAN + i * 16 + col;
        af[i] = *(const bf16x8*)(As + rr * 64 + (((h << 2) | quad) ^ (rr & 7)) * 8);
      }
#pragma unroll
      for (int j = 0; j < NJ; ++j) {
        const int rr = wn * NSPAN + j * 16 + col;
        bfr[j] = *(const bf16x8*)(Bs + rr * 64 + (((h << 2) | quad) ^ (rr & 7)) * 8);
      }
#pragma unroll
      for (int i = 0; i < MI; ++i)
#pragma unroll
        for (int j = 0; j < NJ; ++j)
          acc[i][j] = __builtin_amdgcn_mfma_f32_16x16x32_bf16(af[i], bfr[j], acc[i][j], 0, 0, 0);
    }
  }
#pragma unroll
  for (int i = 0; i < MI; ++i) {
    const int mrow = m0 + wm * MSPAN + i * 16 + quad * 4;
#pragma unroll
    for (int j = 0; j < NJ; ++j) {
      const int n = n0 + wn * NSPAN + j * 16 + col;
      const float bn = SPLITK ? 0.f : bias[n];
      if (VSPLIT && n0 >= 2048) {
        ushort4 o4;
        o4.x = f2bf(acc[i][j][0] + bn);
        o4.y = f2bf(acc[i][j][1] + bn);
        o4.z = f2bf(acc[i][j][2] + bn);
        o4.w = f2bf(acc[i][j][3] + bn);
        *(ushort4*)((unsigned short*)C1 + (size_t)(n - 2048) * 4096 + mrow) = o4;
        continue;
      }
#pragma unroll
      for (int r = 0; r < 4; ++r) {
        const int m = mrow + r;
        if (SPLITK) {
          unsigned short* P = bz == 0 ? (unsigned short*)C0
                            : bz == 1 ? (unsigned short*)C1
                            : bz == 2 ? (unsigned short*)C2
                                      : (unsigned short*)C3;
          P[(size_t)m * N + n] = f2bf(acc[i][j][r]);
        } else {
          float v = acc[i][j][r] + bn;
          if (RELU) v = fmaxf(v, 0.f);
          if (OUT_BF16) ((unsigned short*)C0)[(size_t)m * N + n] = f2bf(v);
          else          ((float*)C0)[(size_t)m * N + n] = v;
        }
      }
    }
  }
}

// ---- MX-fp8 MFMA GEMM, 128x128 tile, BK=128 (rows 128 B, same slot math).
// A:[M][lda] fp8, Bt:[N][ldb] fp8. Unit E8M0 scales (0x7F) = plain fp8 at
// the 2x MX rate. FP8OUT: relu+bias -> fp8 bytes (hb). Else SPLITK bf16
// partials. RX/RY region swizzle as elsewhere.
template <bool FP8OUT, int RX, int RY>
__global__ __launch_bounds__(256, 4) void mfma_gemm_fp8(
    const unsigned char* __restrict__ A, const unsigned char* __restrict__ Bt,
    const float* __restrict__ bias,
    void* __restrict__ C0, void* __restrict__ C1,
    void* __restrict__ C2, void* __restrict__ C3,
    int N, int lda, int ldb, int KH) {
  __shared__ __align__(16) unsigned char As[128 * 128];
  __shared__ __align__(16) unsigned char Bs[128 * 128];
  const int tid = threadIdx.x, lane = tid & 63;
  const int w = tid >> 6;
  const int quad = lane >> 4, col = lane & 15;
  const int wm = w & 1, wn = w >> 1;

  int bx = blockIdx.x, by = blockIdx.y, bz = blockIdx.z;
  {
    const int gx = gridDim.x, gy = gridDim.y;
    const int L = bx + gx * (by + gy * bz);
    const int r = L & 7, s = L >> 3;
    const int nrx = gx / RX, nry = gy / RY;
    const int rx = r % nrx, rem = r / nrx;
    const int ry = rem % nry, rz = rem / nry;
    bx = rx * RX + s % RX;
    by = ry * RY + (s / RX) % RY;
    bz = rz;
  }
  const int m0 = by * 128, n0 = bx * 128;
  const int koff = FP8OUT ? 0 : bz * KH;

  f32x4 acc[4][4];
  const f32x4 z4 = {0.f, 0.f, 0.f, 0.f};
#pragma unroll
  for (int i = 0; i < 4; ++i)
#pragma unroll
    for (int j = 0; j < 4; ++j) acc[i][j] = z4;

  for (int k0 = 0; k0 < KH; k0 += 128) {
    __syncthreads();
#pragma unroll
    for (int t = 0; t < 4; ++t) {  // A: 128 rows x 8 chunks(16B)
      const int s = t * 256 + tid;
      const int r = s >> 3, c = (s & 7) ^ (r & 7);
      g2l16(A + (size_t)(m0 + r) * lda + koff + k0 + c * 16, (void*)(As + s * 16));
    }
#pragma unroll
    for (int t = 0; t < 4; ++t) {
      const int s = t * 256 + tid;
      const int r = s >> 3, c = (s & 7) ^ (r & 7);
      g2l16(Bt + (size_t)(n0 + r) * ldb + koff + k0 + c * 16, (void*)(Bs + s * 16));
    }
    __syncthreads();
    // A-frag: lane holds A[m=rr][k = quad*32 .. +32) = global chunks 2q,2q+1
    i32x8 af[4];
#pragma unroll
    for (int i = 0; i < 4; ++i) {
      const int rr = wm * 64 + i * 16 + col;
      const i32x4* rowp = (const i32x4*)(As + rr * 128);
      const i32x4 lo = rowp[(2 * quad) ^ (rr & 7)];
      const i32x4 hi = rowp[(2 * quad + 1) ^ (rr & 7)];
      af[i] = __builtin_shufflevector(lo, hi, 0, 1, 2, 3, 4, 5, 6, 7);
    }
#pragma unroll
    for (int j = 0; j < 4; ++j) {
      const int rr = wn * 64 + j * 16 + col;
      const i32x4* rowp = (const i32x4*)(Bs + rr * 128);
      const i32x4 lo = rowp[(2 * quad) ^ (rr & 7)];
      const i32x4 hi = rowp[(2 * quad + 1) ^ (rr & 7)];
      const i32x8 bfj = __builtin_shufflevector(lo, hi, 0, 1, 2, 3, 4, 5, 6, 7);
#pragma unroll
      for (int i = 0; i < 4; ++i)
        acc[i][j] = __builtin_amdgcn_mfma_scale_f32_16x16x128_f8f6f4(
            af[i], bfj, acc[i][j], 0, 0, 0, 0x7F7F7F7Fu, 0, 0x7F7F7F7Fu);
    }
  }
#pragma unroll
  for (int i = 0; i < 4; ++i) {
    const int mrow = m0 + wm * 64 + i * 16 + quad * 4;
#pragma unroll
    for (int j = 0; j < 4; ++j) {
      const int n = n0 + wn * 64 + j * 16 + col;
      const float bn = FP8OUT ? bias[n] : 0.f;
#pragma unroll
      for (int r = 0; r < 4; ++r) {
        const int m = mrow + r;
        if (FP8OUT) {
          const float v = fmaxf(acc[i][j][r] + bn, 0.f);
          const unsigned int p = __builtin_amdgcn_cvt_pk_fp8_f32(v, v, 0, false);
          ((unsigned char*)C0)[(size_t)m * N + n] = (unsigned char)(p & 0xFF);
        } else {
          unsigned short* P = bz == 0 ? (unsigned short*)C0
                            : bz == 1 ? (unsigned short*)C1
                            : bz == 2 ? (unsigned short*)C2
                                      : (unsigned short*)C3;
          P[(size_t)m * N + n] = f2bf(acc[i][j][r]);
        }
      }
    }
  }
}

// ---- corr[b*1024+hd] = sum_{tok: mask==0} V[tok][hd]  (coalesced, rnd-11).
__global__ __launch_bounds__(256) void masksum_kernel(
    const unsigned short* __restrict__ vT, const int* __restrict__ mask,
    float* __restrict__ corr) {
  const int hd = blockIdx.x, t = threadIdx.x;
  const int lane = t & 63, w = t >> 6;
  float sb[4];
#pragma unroll
  for (int b = 0; b < 4; ++b) {
    const ushort4 v4 = *(const ushort4*)(vT + (size_t)hd * 4096 + b * 1024 + t * 4);
    const int4 m4 = *(const int4*)(mask + b * 1024 + t * 4);
    float s = 0.f;
    if (m4.x == 0) s += bf2f(v4.x);
    if (m4.y == 0) s += bf2f(v4.y);
    if (m4.z == 0) s += bf2f(v4.z);
    if (m4.w == 0) s += bf2f(v4.w);
#pragma unroll
    for (int off = 32; off > 0; off >>= 1) s += __shfl_down(s, off, 64);
    sb[b] = s;
  }
  __shared__ float red[4][4];
  if (lane == 0) {
    red[w][0] = sb[0]; red[w][1] = sb[1]; red[w][2] = sb[2]; red[w][3] = sb[3];
  }
  __syncthreads();
  if (t < 4)
    corr[t * 1024 + hd] = red[0][t] + red[1][t] + red[2][t] + red[3][t];
}

// ---- combine wo partials + x + bo -> x1 (bf16) ; xn2 = LN2 -> fp8.
__global__ __launch_bounds__(256) void combine_ln_kernel(
    const unsigned short* __restrict__ p0, const unsigned short* __restrict__ p1,
    const float* __restrict__ x, const float* __restrict__ bo,
    const float* __restrict__ alpha, const float* __restrict__ beta,
    unsigned short* __restrict__ x1, unsigned char* __restrict__ xn2f8) {
  const int row = blockIdx.x, t = threadIdx.x;
  const size_t i = (size_t)row * 256 + t;
  const ushort4 a4 = ((const ushort4*)p0)[i];
  const ushort4 b4 = ((const ushort4*)p1)[i];
  const float4 x4 = ((const float4*)x)[i];
  const float4 o4 = ((const float4*)bo)[t];
  float4 v;
  v.x = bf2f(a4.x) + bf2f(b4.x) + x4.x + o4.x;
  v.y = bf2f(a4.y) + bf2f(b4.y) + x4.y + o4.y;
  v.z = bf2f(a4.z) + bf2f(b4.z) + x4.z + o4.z;
  v.w = bf2f(a4.w) + bf2f(b4.w) + x4.w + o4.w;
  ushort4 xb;
  xb.x = f2bf(v.x); xb.y = f2bf(v.y); xb.z = f2bf(v.z); xb.w = f2bf(v.w);
  ((ushort4*)x1)[i] = xb;
  float s  = v.x + v.y + v.z + v.w;
  float ss = v.x * v.x + v.y * v.y + v.z * v.z + v.w * v.w;
#pragma unroll
  for (int off = 32; off > 0; off >>= 1) {
    s  += __shfl_down(s, off, 64);
    ss += __shfl_down(ss, off, 64);
  }
  __shared__ float red[8];
  const int lane = t & 63, wv_ = t >> 6;
  if (lane == 0) { red[wv_] = s; red[4 + wv_] = ss; }
  __syncthreads();
  const float S  = red[0] + red[1] + red[2] + red[3];
  const float SS = red[4] + red[5] + red[6] + red[7];
  const float mean = S * (1.0f / 1024.0f);
  float var = (SS - 1024.0f * mean * mean) * (1.0f / 1023.0f);
  var = fmaxf(var, 0.0f);
  const float scl = alpha[0] / (sqrtf(var) + EPS);
  const float bb = beta[0];
  ((unsigned int*)xn2f8)[i] = pk_fp8x4((v.x - mean) * scl + bb,
                                       (v.y - mean) * scl + bb,
                                       (v.z - mean) * scl + bb,
                                       (v.w - mean) * scl + bb);
}

// ---- combine ffn2 partials (4x bf16) + x1 (bf16) + b2 -> out fp32.
__global__ __launch_bounds__(256) void combine_out_kernel(
    const unsigned short* __restrict__ pf0, const unsigned short* __restrict__ pf1,
    const unsigned short* __restrict__ pf2, const unsigned short* __restrict__ pf3,
    const unsigned short* __restrict__ x1, const float* __restrict__ b2,
    float* __restrict__ out) {
  const int t = threadIdx.x;
  const size_t i = (size_t)blockIdx.x * 256 + t;
  const ushort4 a4 = ((const ushort4*)pf0)[i];
  const ushort4 b4 = ((const ushort4*)pf1)[i];
  const ushort4 c4 = ((const ushort4*)pf2)[i];
  const ushort4 d4 = ((const ushort4*)pf3)[i];
  const ushort4 e4 = ((const ushort4*)x1)[i];
  const float4 f4 = ((const float4*)b2)[t];
  float4 v;
  v.x = bf2f(a4.x) + bf2f(b4.x) + bf2f(c4.x) + bf2f(d4.x) + bf2f(e4.x) + f4.x;
  v.y = bf2f(a4.y) + bf2f(b4.y) + bf2f(c4.y) + bf2f(d4.y) + bf2f(e4.y) + f4.y;
  v.z = bf2f(a4.z) + bf2f(b4.z) + bf2f(c4.z) + bf2f(d4.z) + bf2f(e4.z) + f4.z;
  v.w = bf2f(a4.w) + bf2f(b4.w) + bf2f(c4.w) + bf2f(d4.w) + bf2f(e4.w) + f4.w;
  ((float4*)out)[i] = v;
}

// ---- combine attention key-halves + corr -> ctx (bf16)
__global__ __launch_bounds__(256) void attn_combine_kernel(
    const unsigned short* __restrict__ p0, const unsigned short* __restrict__ p1,
    const float* __restrict__ corr, unsigned short* __restrict__ ctx) {
  const int row = blockIdx.x, t = threadIdx.x;
  const size_t i = (size_t)row * 256 + t;
  const ushort4 a4 = ((const ushort4*)p0)[i];
  const ushort4 b4 = ((const ushort4*)p1)[i];
  const float4 c4 = ((const float4*)(corr + (row >> 10) * 1024))[t];
  ushort4 o;
  o.x = f2bf(bf2f(a4.x) + bf2f(b4.x) - 1e9f * c4.x);
  o.y = f2bf(bf2f(a4.y) + bf2f(b4.y) - 1e9f * c4.y);
  o.z = f2bf(bf2f(a4.z) + bf2f(b4.z) - 1e9f * c4.z);
  o.w = f2bf(bf2f(a4.w) + bf2f(b4.w) - 1e9f * c4.w);
  ((ushort4*)ctx)[i] = o;
}

// ---- fused attention, key-split kz=2 (unchanged from round 11).
__global__ __launch_bounds__(256, 4) void attn_kernel(
    const unsigned short* __restrict__ qkb, const unsigned short* __restrict__ vT,
    const int* __restrict__ mask,
    unsigned short* __restrict__ ctxp0, unsigned short* __restrict__ ctxp1) {
  __shared__ __align__(16) unsigned short Qs[128 * 64];
  __shared__ __align__(16) unsigned short Ks[32 * 64];
  __shared__ __align__(16) unsigned short Vs[64 * 32];
  __shared__ __align__(16) unsigned short Ps[128 * 40];
  const int tid = threadIdx.x, lane = tid & 63, w = tid >> 6;
  const int quad = lane >> 4, col = lane & 15;
  const int L = blockIdx.x + 8 * (blockIdx.y + 16 * blockIdx.z);
  const int s_ = L >> 3;
  const int g = (L & 7) * 16 + (s_ >> 3);
  const int q0 = (s_ & 7) * 128;
  const int h = g & 15, bkz = g >> 4;
  const int b = bkz >> 1, kz = bkz & 1;
  const size_t qbase = ((size_t)(b * 1024 + q0)) * 2048 + h * 64;

#pragma unroll
  for (int t = 0; t < 4; ++t) {
    const int s = t * 256 + w * 64 + lane;
    const int m = s >> 3, c = (s & 7) ^ (m & 7);
    g2l16(qkb + qbase + (size_t)m * 2048 + c * 8, (void*)(Qs + s * 8));
  }
  __syncthreads();
  bf16x8 qf[2][2];
#pragma unroll
  for (int qt = 0; qt < 2; ++qt)
#pragma unroll
    for (int kf = 0; kf < 2; ++kf) {
      const int m = (w * 2 + qt) * 16 + col;
      const int c = (kf * 4 + quad) ^ (m & 7);
      qf[qt][kf] = *(const bf16x8*)(Qs + m * 64 + c * 8);
    }

  const f32x4 z4 = {0.f, 0.f, 0.f, 0.f};
  f32x4 oacc[2][4];
#pragma unroll
  for (int qt = 0; qt < 2; ++qt)
#pragma unroll
    for (int nt = 0; nt < 4; ++nt) oacc[qt][nt] = z4;

  const int* mrow = mask + b * 1024;
  const int kb0 = kz * 512;
  for (int kb = kb0; kb < kb0 + 512; kb += 32) {
    __syncthreads();
    {
      const int s = w * 64 + lane;
      const int key = s >> 3, ck = (s & 7) ^ (key & 7);
      g2l16(qkb + ((size_t)(b * 1024 + kb + key)) * 2048 + 1024 + h * 64 + ck * 8,
            (void*)(Ks + s * 8));
      const int d = s >> 2, cv = (s & 3) ^ (((d >> 2) ^ d) & 3);
      g2l16(vT + ((size_t)(h * 64 + d)) * 4096 + b * 1024 + kb + cv * 8,
            (void*)(Vs + s * 8));
    }
    __syncthreads();

    f32x4 st[2][2];
#pragma unroll
    for (int qt = 0; qt < 2; ++qt)
#pragma unroll
      for (int kt = 0; kt < 2; ++kt) st[qt][kt] = z4;
#pragma unroll
    for (int kt = 0; kt < 2; ++kt)
#pragma unroll
      for (int kf = 0; kf < 2; ++kf) {
        const int key = kt * 16 + col;
        const int c = (kf * 4 + quad) ^ (key & 7);
        const bf16x8 kfrag = *(const bf16x8*)(Ks + key * 64 + c * 8);
#pragma unroll
        for (int qt = 0; qt < 2; ++qt)
          st[qt][kt] = __builtin_amdgcn_mfma_f32_16x16x32_bf16(
              kfrag, qf[qt][kf], st[qt][kt], 0, 0, 0);
      }

    const int4 mv0 = *(const int4*)(mrow + kb + quad * 4);
    const int4 mv1 = *(const int4*)(mrow + kb + 16 + quad * 4);
#pragma unroll
    for (int qt = 0; qt < 2; ++qt) {
      const int qrow = (w * 2 + qt) * 16 + col;
#pragma unroll
      for (int kt = 0; kt < 2; ++kt) {
        const int4 mv = kt ? mv1 : mv0;
        const f32x4 sv = st[qt][kt];
        const unsigned int u0 = fbits((mv.x ? 0.125f : 0.f) * sv[0]) + 0x8000u;
        const unsigned int u1 = fbits((mv.y ? 0.125f : 0.f) * sv[1]) + 0x8000u;
        const unsigned int u2 = fbits((mv.z ? 0.125f : 0.f) * sv[2]) + 0x8000u;
        const unsigned int u3 = fbits((mv.w ? 0.125f : 0.f) * sv[3]) + 0x8000u;
        uint2 pk;
        pk.x = (u0 >> 16) | (u1 & 0xFFFF0000u);
        pk.y = (u2 >> 16) | (u3 & 0xFFFF0000u);
        const int pp = kt * 2 + (quad >> 1);
        *(uint2*)(Ps + qrow * 40 + ((pp ^ (qrow & 3)) * 8 + (quad & 1) * 4)) = pk;
      }
    }
    // no barrier: wave w only touches its own q-rows

#pragma unroll
    for (int qt = 0; qt < 2; ++qt) {
      const int qrow = (w * 2 + qt) * 16 + col;
      const bf16x8 pf = *(const bf16x8*)(Ps + qrow * 40 + (quad ^ (qrow & 3)) * 8);
#pragma unroll
      for (int nt = 0; nt < 4; ++nt) {
        const int vr = nt * 16 + col;
        const bf16x8 vf = *(const bf16x8*)(Vs + vr * 32 + ((quad ^ (((vr >> 2) ^ vr) & 3))) * 8);
        oacc[qt][nt] = __builtin_amdgcn_mfma_f32_16x16x32_bf16(pf, vf, oacc[qt][nt], 0, 0, 0);
      }
    }
  }

  unsigned short* P = kz ? ctxp1 : ctxp0;
#pragma unroll
  for (int qt = 0; qt < 2; ++qt)
#pragma unroll
    for (int nt = 0; nt < 4; ++nt) {
      const int d = nt * 16 + col;
#pragma unroll
      for (int r = 0; r < 4; ++r) {
        const int qq = q0 + (w * 2 + qt) * 16 + quad * 4 + r;
        P[((size_t)(b * 1024) + qq) * 1024 + h * 64 + d] = f2bf(oacc[qt][nt][r]);
      }
    }
}

extern "C" void kernel_launch(void* const* d_in, const int* in_sizes, int n_in,
                              void* d_out, int out_size, void* d_ws, size_t ws_size,
                              hipStream_t stream) {
  const float* x    = (const float*)d_in[0];
  const int*   mask = (const int*)d_in[1];
  const float* wq = (const float*)d_in[2];
  const float* bq = (const float*)d_in[3];
  const float* wk = (const float*)d_in[4];
  const float* bk = (const float*)d_in[5];
  const float* wv = (const float*)d_in[6];
  const float* bv = (const float*)d_in[7];
  const float* wo = (const float*)d_in[8];
  const float* bo = (const float*)d_in[9];
  const float* w1 = (const float*)d_in[10];
  const float* b1 = (const float*)d_in[11];
  const float* w2 = (const float*)d_in[12];
  const float* b2 = (const float*)d_in[13];
  const float* ln1a = (const float*)d_in[14];
  const float* ln1b = (const float*)d_in[15];
  const float* ln2a = (const float*)d_in[16];
  const float* ln2b = (const float*)d_in[17];
  float* out = (float*)d_out;
  char* W = (char*)d_ws;
  const size_t MB = 1u << 20;

  unsigned short* wqkvT = (unsigned short*)(W + 0 * MB);   // 6 MB [3072][1024]
  unsigned short* woT   = (unsigned short*)(W + 6 * MB);   // 2 MB
  unsigned char*  w1F8  = (unsigned char*)(W + 8 * MB);    // 4 MB [4096][1024]
  unsigned char*  w2F8  = (unsigned char*)(W + 16 * MB);   // 4 MB [1024][4096]
  float*          bqkv  = (float*)(W + 24 * MB);           // 12 KB
  float*          corr  = (float*)(W + 24 * MB + 65536);   // 16 KB
  unsigned short* xn    = (unsigned short*)(W + 25 * MB);  // 8 MB
  unsigned char*  xn2f8 = (unsigned char*)(W + 25 * MB);   // 4 MB (xn dead)
  unsigned short* qkb   = (unsigned short*)(W + 33 * MB);  // 16 MB [4096][2048]
  unsigned short* vT    = (unsigned short*)(W + 49 * MB);  // 8 MB [1024][4096]
  unsigned short* ctxp0 = (unsigned short*)(W + 57 * MB);  // 8 MB
  unsigned short* ctxp1 = (unsigned short*)(W + 65 * MB);  // 8 MB
  unsigned short* ctx   = (unsigned short*)(W + 33 * MB);  // 8 MB (qkb dead)
  unsigned short* p0wo  = (unsigned short*)(W + 41 * MB);  // 8 MB (qkb dead)
  unsigned short* p1wo  = (unsigned short*)(W + 49 * MB);  // 8 MB (vT dead)
  unsigned short* x1    = (unsigned short*)(W + 73 * MB);  // 8 MB
  unsigned char*  hbF8  = (unsigned char*)(W + 33 * MB);   // 16 MB (33-49 dead)
  unsigned short* pf0   = (unsigned short*)(W + 0 * MB);   // 8 MB (wqkvT/woT dead)
  unsigned short* pf1   = (unsigned short*)(W + 49 * MB);  // 8 MB (p1wo dead)
  unsigned short* pf2   = (unsigned short*)(W + 65 * MB);  // 8 MB (ctxp1 dead)
  unsigned short* pf3   = (unsigned short*)(W + 57 * MB);  // 8 MB (ctxp0 dead)

  wconv_ln_kernel<<<7169, 256, 0, stream>>>(wq, wk, wv, wo, w1, w2, bq, bk, bv,
                                            wqkvT, woT, w1F8, w2F8, bqkv,
                                            x, xn, ln1a, ln1b);
  // fused q|k|v GEMM (bf16 — V-path precision): 768 blocks, BK=64
  mfma_gemm<128, 128, true, false, false, true, 12, 8>
      <<<dim3(24, 32), 256, 0, stream>>>(
      xn, wqkvT, bqkv, qkb, vT, nullptr, nullptr, 2048, 1024, 1024, 1024);
  masksum_kernel<<<1024, 256, 0, stream>>>(vT, mask, corr);
  attn_kernel<<<dim3(8, 16, 8), 256, 0, stream>>>(qkb, vT, mask, ctxp0, ctxp1);
  attn_combine_kernel<<<4096, 256, 0, stream>>>(ctxp0, ctxp1, corr, ctx);
  // wo-proj split-K z=2 (bf16)
  mfma_gemm<128, 128, false, false, true, false, 8, 8>
      <<<dim3(8, 32, 2), 256, 0, stream>>>(
      ctx, woT, nullptr, p0wo, p1wo, nullptr, nullptr, 1024, 1024, 1024, 512);
  combine_ln_kernel<<<4096, 256, 0, stream>>>(p0wo, p1wo, x, bo, ln2a, ln2b, x1, xn2f8);
  // FFN1 fp8: 1024 blocks, BK=128, relu+fp8 out
  mfma_gemm_fp8<true, 16, 8><<<dim3(32, 32), 256, 0, stream>>>(
      xn2f8, w1F8, b1, hbF8, nullptr, nullptr, nullptr, 4096, 1024, 1024, 1024);
  // FFN2 fp8 split-K z=4: 1024 blocks, bf16 partials
  mfma_gemm_fp8<false, 8, 16><<<dim3(8, 32, 4), 256, 0, stream>>>(
      hbF8, w2F8, nullptr, pf0, pf1, pf2, pf3, 1024, 4096, 4096, 1024);
  combine_out_kernel<<<4096, 256, 0, stream>>>(pf0, pf1, pf2, pf3, x1, b2, out);
}

// Round 13
// 285.391 us; speedup vs baseline: 1.2250x; 1.0519x over previous
//
#include <hip/hip_runtime.h>
#include <hip/hip_bf16.h>
#include <math.h>

// ---------------------------------------------------------------------------
// EncoderBlock, round 13: split-K eliminated; epilogue fusion.
//  - wo-proj: TM128xTN64 z=1 (512 blocks, same 16-MFMA/barrier density),
//    epilogue fuses +bo +x -> x1 bf16. combine_ln -> pure LN2 (8 MB read).
//  - ffn2: fp8 TM128xTN64 z=1, K=4096 in-kernel (8 K128-MFMA/barrier),
//    epilogue fuses +b2 +x1 -> out fp32. combine_out DELETED.
//  - qkv GEMM, attention (kz=2 + combine), masksum, ffn1 unchanged from r12.
// ---------------------------------------------------------------------------

#define EPS 1e-5f

typedef __attribute__((ext_vector_type(8))) short bf16x8;
typedef __attribute__((ext_vector_type(4))) float f32x4;
typedef __attribute__((ext_vector_type(8))) int i32x8;
typedef __attribute__((ext_vector_type(4))) int i32x4;

typedef const __attribute__((address_space(1))) unsigned char glob_byte;
typedef __attribute__((address_space(3))) unsigned char lds_byte;

__device__ __forceinline__ void g2l16(const void* g, void* l) {
  __builtin_amdgcn_global_load_lds((glob_byte*)g, (lds_byte*)l, 16, 0, 0);
}

__device__ __forceinline__ unsigned short f2bf(float f) {
  union { float f; unsigned int u; } v; v.f = f;
  return (unsigned short)((v.u + 0x7FFFu + ((v.u >> 16) & 1u)) >> 16);
}
__device__ __forceinline__ float bf2f(unsigned short b) {
  union { unsigned int u; float f; } v; v.u = (unsigned int)b << 16;
  return v.f;
}
__device__ __forceinline__ unsigned int fbits(float f) {
  union { float f; unsigned int u; } v; v.f = f;
  return v.u;
}
__device__ __forceinline__ unsigned int pk_fp8x4(float a, float b, float c, float d) {
  unsigned int p = 0;
  p = __builtin_amdgcn_cvt_pk_fp8_f32(a, b, p, false);
  p = __builtin_amdgcn_cvt_pk_fp8_f32(c, d, p, true);
  return p;
}

// ---- weights: wq..wo -> bf16 [N][K]; w1/w2 -> fp8 [N][K]; qkv bias; LN1.
__global__ __launch_bounds__(256) void wconv_ln_kernel(
    const float* __restrict__ wq, const float* __restrict__ wk,
    const float* __restrict__ wv, const float* __restrict__ wo,
    const float* __restrict__ w1, const float* __restrict__ w2,
    const float* __restrict__ bq, const float* __restrict__ bk,
    const float* __restrict__ bv,
    unsigned short* __restrict__ wqkvT, unsigned short* __restrict__ woT,
    unsigned char* __restrict__ w1F8, unsigned char* __restrict__ w2F8,
    float* __restrict__ bqkv,
    const float* __restrict__ x, unsigned short* __restrict__ xn,
    const float* __restrict__ ln1a, const float* __restrict__ ln1b) {
  __shared__ float tile[64][65];
  const int bid = blockIdx.x;
  const int t = threadIdx.x;
  if (bid >= 3073) {  // ---- LayerNorm1 (torch: ddof=1, /(std+eps))
    const int row = bid - 3073;
    const float4 v = ((const float4*)(x + (size_t)row * 1024))[t];
    float s  = v.x + v.y + v.z + v.w;
    float ss = v.x * v.x + v.y * v.y + v.z * v.z + v.w * v.w;
#pragma unroll
    for (int off = 32; off > 0; off >>= 1) {
      s  += __shfl_down(s, off, 64);
      ss += __shfl_down(ss, off, 64);
    }
    __shared__ float red[8];
    const int lane = t & 63, wv_ = t >> 6;
    if (lane == 0) { red[wv_] = s; red[4 + wv_] = ss; }
    __syncthreads();
    const float S  = red[0] + red[1] + red[2] + red[3];
    const float SS = red[4] + red[5] + red[6] + red[7];
    const float mean = S * (1.0f / 1024.0f);
    float var = (SS - 1024.0f * mean * mean) * (1.0f / 1023.0f);
    var = fmaxf(var, 0.0f);
    const float scl = ln1a[0] / (sqrtf(var) + EPS);
    const float b = ln1b[0];
    ushort4 o;
    o.x = f2bf((v.x - mean) * scl + b);
    o.y = f2bf((v.y - mean) * scl + b);
    o.z = f2bf((v.z - mean) * scl + b);
    o.w = f2bf((v.w - mean) * scl + b);
    ((ushort4*)(xn + (size_t)row * 1024))[t] = o;
    return;
  }
  if (bid == 3072) {
#pragma unroll
    for (int i = 0; i < 12; ++i) {
      const int n = i * 256 + t;
      bqkv[n] = n < 1024 ? bq[n] : (n < 2048 ? bk[n - 1024] : bv[n - 2048]);
    }
    return;
  }
  const float* src; int K, N, tk, tn;
  unsigned short* dst16 = nullptr; unsigned char* dst8 = nullptr;
  if (bid < 1024) {
    const int m = bid >> 8, loc = bid & 255;
    src = m == 0 ? wq : m == 1 ? wk : m == 2 ? wv : wo;
    dst16 = m == 3 ? woT : (wqkvT + (size_t)m * 1024 * 1024);
    K = 1024; N = 1024; tk = loc >> 4; tn = loc & 15;
  } else if (bid < 2048) {
    const int loc = bid - 1024; src = w1; dst8 = w1F8;
    K = 1024; N = 4096; tk = loc >> 6; tn = loc & 63;
  } else {
    const int loc = bid - 2048; src = w2; dst8 = w2F8;
    K = 4096; N = 1024; tk = loc >> 4; tn = loc & 15;
  }
  const int lr = t >> 4, lc = (t & 15) * 4;
#pragma unroll
  for (int i = 0; i < 4; ++i) {
    const float4 v = *(const float4*)(src + (size_t)(tk * 64 + lr + 16 * i) * N + tn * 64 + lc);
    tile[lr + 16 * i][lc + 0] = v.x;
    tile[lr + 16 * i][lc + 1] = v.y;
    tile[lr + 16 * i][lc + 2] = v.z;
    tile[lr + 16 * i][lc + 3] = v.w;
  }
  __syncthreads();
  const int on = t >> 2, ok = (t & 3) * 16;
#pragma unroll
  for (int jj = 0; jj < 4; ++jj) {
    if (dst8) {
      const unsigned int p = pk_fp8x4(tile[ok + 4 * jj + 0][on], tile[ok + 4 * jj + 1][on],
                                      tile[ok + 4 * jj + 2][on], tile[ok + 4 * jj + 3][on]);
      *(unsigned int*)(dst8 + (size_t)(tn * 64 + on) * K + tk * 64 + ok + 4 * jj) = p;
    } else {
      ushort4 o4;
      o4.x = f2bf(tile[ok + 4 * jj + 0][on]);
      o4.y = f2bf(tile[ok + 4 * jj + 1][on]);
      o4.z = f2bf(tile[ok + 4 * jj + 2][on]);
      o4.w = f2bf(tile[ok + 4 * jj + 3][on]);
      *(ushort4*)(dst16 + (size_t)(tn * 64 + on) * K + tk * 64 + ok + 4 * jj) = o4;
    }
  }
}

// ---- bf16 MFMA GEMM, BK=64, TMxTN, z=1.
// RES: epilogue adds fp32 res[m][n]. VSPLIT: n0>=2048 tiles store transposed
// (+bias) into C1 = vT[hd][tok]. RX/RY: 2D region swizzle (nrx*nry == 8).
template <int TM, int TN, bool OUT_BF16, bool RELU, bool RES, bool VSPLIT,
          int RX, int RY>
__global__ __launch_bounds__(256, 4) void mfma_gemm(
    const unsigned short* __restrict__ A, const unsigned short* __restrict__ Bt,
    const float* __restrict__ bias, const float* __restrict__ res,
    void* __restrict__ C0, void* __restrict__ C1,
    int N, int lda, int ldb, int KH) {
  constexpr int WM = 2, WN = 2;
  constexpr int MSPAN = TM / WM, NSPAN = TN / WN;
  constexpr int MI = MSPAN / 16, NJ = NSPAN / 16;
  __shared__ __align__(16) unsigned short As[TM * 64];
  __shared__ __align__(16) unsigned short Bs[TN * 64];
  const int tid = threadIdx.x, lane = tid & 63;
  const int w = tid >> 6;
  const int quad = lane >> 4, col = lane & 15;
  const int wm = w % WM, wn = w / WM;

  int bx = blockIdx.x, by = blockIdx.y;
  {
    const int gx = gridDim.x, gy = gridDim.y;
    const int L = bx + gx * by;
    const int r = L & 7, s = L >> 3;
    const int nrx = gx / RX;
    const int rx = r % nrx, ry = r / nrx;
    bx = rx * RX + s % RX;
    by = ry * RY + (s / RX) % RY;
  }
  const int m0 = by * TM, n0 = bx * TN;

  f32x4 acc[MI][NJ];
  const f32x4 z4 = {0.f, 0.f, 0.f, 0.f};
#pragma unroll
  for (int i = 0; i < MI; ++i)
#pragma unroll
    for (int j = 0; j < NJ; ++j) acc[i][j] = z4;

  for (int k0 = 0; k0 < KH; k0 += 64) {
    __syncthreads();
#pragma unroll
    for (int t = 0; t < TM / 32; ++t) {
      const int s = t * 256 + tid;
      const int r = s >> 3, c = (s & 7) ^ (r & 7);
      g2l16(A + (size_t)(m0 + r) * lda + k0 + c * 8, (void*)(As + s * 8));
    }
#pragma unroll
    for (int t = 0; t < TN / 32; ++t) {
      const int s = t * 256 + tid;
      const int r = s >> 3, c = (s & 7) ^ (r & 7);
      g2l16(Bt + (size_t)(n0 + r) * ldb + k0 + c * 8, (void*)(Bs + s * 8));
    }
    __syncthreads();
#pragma unroll
    for (int h = 0; h < 2; ++h) {
      bf16x8 af[MI], bfr[NJ];
#pragma unroll
      for (int i = 0; i < MI; ++i) {
        const int rr = wm * MSPAN + i * 16 + col;
        af[i] = *(const bf16x8*)(As + rr * 64 + (((h << 2) | quad) ^ (rr & 7)) * 8);
      }
#pragma unroll
      for (int j = 0; j < NJ; ++j) {
        const int rr = wn * NSPAN + j * 16 + col;
        bfr[j] = *(const bf16x8*)(Bs + rr * 64 + (((h << 2) | quad) ^ (rr & 7)) * 8);
      }
#pragma unroll
      for (int i = 0; i < MI; ++i)
#pragma unroll
        for (int j = 0; j < NJ; ++j)
          acc[i][j] = __builtin_amdgcn_mfma_f32_16x16x32_bf16(af[i], bfr[j], acc[i][j], 0, 0, 0);
    }
  }
#pragma unroll
  for (int i = 0; i < MI; ++i) {
    const int mrow = m0 + wm * MSPAN + i * 16 + quad * 4;
#pragma unroll
    for (int j = 0; j < NJ; ++j) {
      const int n = n0 + wn * NSPAN + j * 16 + col;
      const float bn = bias[n];
      if (VSPLIT && n0 >= 2048) {
        ushort4 o4;
        o4.x = f2bf(acc[i][j][0] + bn);
        o4.y = f2bf(acc[i][j][1] + bn);
        o4.z = f2bf(acc[i][j][2] + bn);
        o4.w = f2bf(acc[i][j][3] + bn);
        *(ushort4*)((unsigned short*)C1 + (size_t)(n - 2048) * 4096 + mrow) = o4;
        continue;
      }
#pragma unroll
      for (int r = 0; r < 4; ++r) {
        const int m = mrow + r;
        float v = acc[i][j][r] + bn;
        if (RES)  v += res[(size_t)m * N + n];
        if (RELU) v = fmaxf(v, 0.f);
        if (OUT_BF16) ((unsigned short*)C0)[(size_t)m * N + n] = f2bf(v);
        else          ((float*)C0)[(size_t)m * N + n] = v;
      }
    }
  }
}

// ---- MX-fp8 MFMA GEMM, TM=128 x TN, BK=128, z=1. Unit E8M0 scales.
// FP8OUT: relu+bias -> fp8 (ffn1/hb). Else: +bias +bf16 res -> fp32 (ffn2/out).
template <bool FP8OUT, int TN, int RX, int RY>
__global__ __launch_bounds__(256, 4) void mfma_gemm_fp8(
    const unsigned char* __restrict__ A, const unsigned char* __restrict__ Bt,
    const float* __restrict__ bias, const unsigned short* __restrict__ res16,
    void* __restrict__ C0, int N, int lda, int ldb, int KH) {
  constexpr int NSPAN = TN / 2;
  constexpr int NJ = NSPAN / 16;
  __shared__ __align__(16) unsigned char As[128 * 128];
  __shared__ __align__(16) unsigned char Bs[TN * 128];
  const int tid = threadIdx.x, lane = tid & 63;
  const int w = tid >> 6;
  const int quad = lane >> 4, col = lane & 15;
  const int wm = w & 1, wn = w >> 1;

  int bx = blockIdx.x, by = blockIdx.y;
  {
    const int gx = gridDim.x, gy = gridDim.y;
    const int L = bx + gx * by;
    const int r = L & 7, s = L >> 3;
    const int nrx = gx / RX;
    const int rx = r % nrx, ry = r / nrx;
    bx = rx * RX + s % RX;
    by = ry * RY + (s / RX) % RY;
  }
  const int m0 = by * 128, n0 = bx * TN;

  f32x4 acc[4][NJ];
  const f32x4 z4 = {0.f, 0.f, 0.f, 0.f};
#pragma unroll
  for (int i = 0; i < 4; ++i)
#pragma unroll
    for (int j = 0; j < NJ; ++j) acc[i][j] = z4;

  for (int k0 = 0; k0 < KH; k0 += 128) {
    __syncthreads();
#pragma unroll
    for (int t = 0; t < 4; ++t) {
      const int s = t * 256 + tid;
      const int r = s >> 3, c = (s & 7) ^ (r & 7);
      g2l16(A + (size_t)(m0 + r) * lda + k0 + c * 16, (void*)(As + s * 16));
    }
#pragma unroll
    for (int t = 0; t < TN / 32; ++t) {
      const int s = t * 256 + tid;
      const int r = s >> 3, c = (s & 7) ^ (r & 7);
      g2l16(Bt + (size_t)(n0 + r) * ldb + k0 + c * 16, (void*)(Bs + s * 16));
    }
    __syncthreads();
    i32x8 af[4];
#pragma unroll
    for (int i = 0; i < 4; ++i) {
      const int rr = wm * 64 + i * 16 + col;
      const i32x4* rowp = (const i32x4*)(As + rr * 128);
      const i32x4 lo = rowp[(2 * quad) ^ (rr & 7)];
      const i32x4 hi = rowp[(2 * quad + 1) ^ (rr & 7)];
      af[i] = __builtin_shufflevector(lo, hi, 0, 1, 2, 3, 4, 5, 6, 7);
    }
#pragma unroll
    for (int j = 0; j < NJ; ++j) {
      const int rr = wn * NSPAN + j * 16 + col;
      const i32x4* rowp = (const i32x4*)(Bs + rr * 128);
      const i32x4 lo = rowp[(2 * quad) ^ (rr & 7)];
      const i32x4 hi = rowp[(2 * quad + 1) ^ (rr & 7)];
      const i32x8 bfj = __builtin_shufflevector(lo, hi, 0, 1, 2, 3, 4, 5, 6, 7);
#pragma unroll
      for (int i = 0; i < 4; ++i)
        acc[i][j] = __builtin_amdgcn_mfma_scale_f32_16x16x128_f8f6f4(
            af[i], bfj, acc[i][j], 0, 0, 0, 0x7F7F7F7Fu, 0, 0x7F7F7F7Fu);
    }
  }
#pragma unroll
  for (int i = 0; i < 4; ++i) {
    const int mrow = m0 + wm * 64 + i * 16 + quad * 4;
#pragma unroll
    for (int j = 0; j < NJ; ++j) {
      const int n = n0 + wn * NSPAN + j * 16 + col;
      const float bn = bias[n];
#pragma unroll
      for (int r = 0; r < 4; ++r) {
        const int m = mrow + r;
        if (FP8OUT) {
          const float v = fmaxf(acc[i][j][r] + bn, 0.f);
          const unsigned int p = __builtin_amdgcn_cvt_pk_fp8_f32(v, v, 0, false);
          ((unsigned char*)C0)[(size_t)m * N + n] = (unsigned char)(p & 0xFF);
        } else {
          const float v = acc[i][j][r] + bn + bf2f(res16[(size_t)m * N + n]);
          ((float*)C0)[(size_t)m * N + n] = v;
        }
      }
    }
  }
}

// ---- corr[b*1024+hd] = sum_{tok: mask==0} V[tok][hd]  (coalesced).
__global__ __launch_bounds__(256) void masksum_kernel(
    const unsigned short* __restrict__ vT, const int* __restrict__ mask,
    float* __restrict__ corr) {
  const int hd = blockIdx.x, t = threadIdx.x;
  const int lane = t & 63, w = t >> 6;
  float sb[4];
#pragma unroll
  for (int b = 0; b < 4; ++b) {
    const ushort4 v4 = *(const ushort4*)(vT + (size_t)hd * 4096 + b * 1024 + t * 4);
    const int4 m4 = *(const int4*)(mask + b * 1024 + t * 4);
    float s = 0.f;
    if (m4.x == 0) s += bf2f(v4.x);
    if (m4.y == 0) s += bf2f(v4.y);
    if (m4.z == 0) s += bf2f(v4.z);
    if (m4.w == 0) s += bf2f(v4.w);
#pragma unroll
    for (int off = 32; off > 0; off >>= 1) s += __shfl_down(s, off, 64);
    sb[b] = s;
  }
  __shared__ float red[4][4];
  if (lane == 0) {
    red[w][0] = sb[0]; red[w][1] = sb[1]; red[w][2] = sb[2]; red[w][3] = sb[3];
  }
  __syncthreads();
  if (t < 4)
    corr[t * 1024 + hd] = red[0][t] + red[1][t] + red[2][t] + red[3][t];
}

// ---- LN2: x1 bf16 -> xn2 fp8 (torch semantics).
__global__ __launch_bounds__(256) void ln2_kernel(
    const unsigned short* __restrict__ x1,
    const float* __restrict__ alpha, const float* __restrict__ beta,
    unsigned char* __restrict__ xn2f8) {
  const int row = blockIdx.x, t = threadIdx.x;
  const size_t i = (size_t)row * 256 + t;
  const ushort4 a4 = ((const ushort4*)x1)[i];
  float4 v;
  v.x = bf2f(a4.x); v.y = bf2f(a4.y); v.z = bf2f(a4.z); v.w = bf2f(a4.w);
  float s  = v.x + v.y + v.z + v.w;
  float ss = v.x * v.x + v.y * v.y + v.z * v.z + v.w * v.w;
#pragma unroll
  for (int off = 32; off > 0; off >>= 1) {
    s  += __shfl_down(s, off, 64);
    ss += __shfl_down(ss, off, 64);
  }
  __shared__ float red[8];
  const int lane = t & 63, wv_ = t >> 6;
  if (lane == 0) { red[wv_] = s; red[4 + wv_] = ss; }
  __syncthreads();
  const float S  = red[0] + red[1] + red[2] + red[3];
  const float SS = red[4] + red[5] + red[6] + red[7];
  const float mean = S * (1.0f / 1024.0f);
  float var = (SS - 1024.0f * mean * mean) * (1.0f / 1023.0f);
  var = fmaxf(var, 0.0f);
  const float scl = alpha[0] / (sqrtf(var) + EPS);
  const float bb = beta[0];
  ((unsigned int*)xn2f8)[i] = pk_fp8x4((v.x - mean) * scl + bb,
                                       (v.y - mean) * scl + bb,
                                       (v.z - mean) * scl + bb,
                                       (v.w - mean) * scl + bb);
}

// ---- combine attention key-halves + corr -> ctx (bf16)
__global__ __launch_bounds__(256) void attn_combine_kernel(
    const unsigned short* __restrict__ p0, const unsigned short* __restrict__ p1,
    const float* __restrict__ corr, unsigned short* __restrict__ ctx) {
  const int row = blockIdx.x, t = threadIdx.x;
  const size_t i = (size_t)row * 256 + t;
  const ushort4 a4 = ((const ushort4*)p0)[i];
  const ushort4 b4 = ((const ushort4*)p1)[i];
  const float4 c4 = ((const float4*)(corr + (row >> 10) * 1024))[t];
  ushort4 o;
  o.x = f2bf(bf2f(a4.x) + bf2f(b4.x) - 1e9f * c4.x);
  o.y = f2bf(bf2f(a4.y) + bf2f(b4.y) - 1e9f * c4.y);
  o.z = f2bf(bf2f(a4.z) + bf2f(b4.z) - 1e9f * c4.z);
  o.w = f2bf(bf2f(a4.w) + bf2f(b4.w) - 1e9f * c4.w);
  ((ushort4*)ctx)[i] = o;
}

// ---- fused attention, key-split kz=2 (unchanged from round 12).
__global__ __launch_bounds__(256, 4) void attn_kernel(
    const unsigned short* __restrict__ qkb, const unsigned short* __restrict__ vT,
    const int* __restrict__ mask,
    unsigned short* __restrict__ ctxp0, unsigned short* __restrict__ ctxp1) {
  __shared__ __align__(16) unsigned short Qs[128 * 64];
  __shared__ __align__(16) unsigned short Ks[32 * 64];
  __shared__ __align__(16) unsigned short Vs[64 * 32];
  __shared__ __align__(16) unsigned short Ps[128 * 40];
  const int tid = threadIdx.x, lane = tid & 63, w = tid >> 6;
  const int quad = lane >> 4, col = lane & 15;
  const int L = blockIdx.x + 8 * (blockIdx.y + 16 * blockIdx.z);
  const int s_ = L >> 3;
  const int g = (L & 7) * 16 + (s_ >> 3);
  const int q0 = (s_ & 7) * 128;
  const int h = g & 15, bkz = g >> 4;
  const int b = bkz >> 1, kz = bkz & 1;
  const size_t qbase = ((size_t)(b * 1024 + q0)) * 2048 + h * 64;

#pragma unroll
  for (int t = 0; t < 4; ++t) {
    const int s = t * 256 + w * 64 + lane;
    const int m = s >> 3, c = (s & 7) ^ (m & 7);
    g2l16(qkb + qbase + (size_t)m * 2048 + c * 8, (void*)(Qs + s * 8));
  }
  __syncthreads();
  bf16x8 qf[2][2];
#pragma unroll
  for (int qt = 0; qt < 2; ++qt)
#pragma unroll
    for (int kf = 0; kf < 2; ++kf) {
      const int m = (w * 2 + qt) * 16 + col;
      const int c = (kf * 4 + quad) ^ (m & 7);
      qf[qt][kf] = *(const bf16x8*)(Qs + m * 64 + c * 8);
    }

  const f32x4 z4 = {0.f, 0.f, 0.f, 0.f};
  f32x4 oacc[2][4];
#pragma unroll
  for (int qt = 0; qt < 2; ++qt)
#pragma unroll
    for (int nt = 0; nt < 4; ++nt) oacc[qt][nt] = z4;

  const int* mrow = mask + b * 1024;
  const int kb0 = kz * 512;
  for (int kb = kb0; kb < kb0 + 512; kb += 32) {
    __syncthreads();
    {
      const int s = w * 64 + lane;
      const int key = s >> 3, ck = (s & 7) ^ (key & 7);
      g2l16(qkb + ((size_t)(b * 1024 + kb + key)) * 2048 + 1024 + h * 64 + ck * 8,
            (void*)(Ks + s * 8));
      const int d = s >> 2, cv = (s & 3) ^ (((d >> 2) ^ d) & 3);
      g2l16(vT + ((size_t)(h * 64 + d)) * 4096 + b * 1024 + kb + cv * 8,
            (void*)(Vs + s * 8));
    }
    __syncthreads();

    f32x4 st[2][2];
#pragma unroll
    for (int qt = 0; qt < 2; ++qt)
#pragma unroll
      for (int kt = 0; kt < 2; ++kt) st[qt][kt] = z4;
#pragma unroll
    for (int kt = 0; kt < 2; ++kt)
#pragma unroll
      for (int kf = 0; kf < 2; ++kf) {
        const int key = kt * 16 + col;
        const int c = (kf * 4 + quad) ^ (key & 7);
        const bf16x8 kfrag = *(const bf16x8*)(Ks + key * 64 + c * 8);
#pragma unroll
        for (int qt = 0; qt < 2; ++qt)
          st[qt][kt] = __builtin_amdgcn_mfma_f32_16x16x32_bf16(
              kfrag, qf[qt][kf], st[qt][kt], 0, 0, 0);
      }

    const int4 mv0 = *(const int4*)(mrow + kb + quad * 4);
    const int4 mv1 = *(const int4*)(mrow + kb + 16 + quad * 4);
#pragma unroll
    for (int qt = 0; qt < 2; ++qt) {
      const int qrow = (w * 2 + qt) * 16 + col;
#pragma unroll
      for (int kt = 0; kt < 2; ++kt) {
        const int4 mv = kt ? mv1 : mv0;
        const f32x4 sv = st[qt][kt];
        const unsigned int u0 = fbits((mv.x ? 0.125f : 0.f) * sv[0]) + 0x8000u;
        const unsigned int u1 = fbits((mv.y ? 0.125f : 0.f) * sv[1]) + 0x8000u;
        const unsigned int u2 = fbits((mv.z ? 0.125f : 0.f) * sv[2]) + 0x8000u;
        const unsigned int u3 = fbits((mv.w ? 0.125f : 0.f) * sv[3]) + 0x8000u;
        uint2 pk;
        pk.x = (u0 >> 16) | (u1 & 0xFFFF0000u);
        pk.y = (u2 >> 16) | (u3 & 0xFFFF0000u);
        const int pp = kt * 2 + (quad >> 1);
        *(uint2*)(Ps + qrow * 40 + ((pp ^ (qrow & 3)) * 8 + (quad & 1) * 4)) = pk;
      }
    }
    // no barrier: wave w only touches its own q-rows

#pragma unroll
    for (int qt = 0; qt < 2; ++qt) {
      const int qrow = (w * 2 + qt) * 16 + col;
      const bf16x8 pf = *(const bf16x8*)(Ps + qrow * 40 + (quad ^ (qrow & 3)) * 8);
#pragma unroll
      for (int nt = 0; nt < 4; ++nt) {
        const int vr = nt * 16 + col;
        const bf16x8 vf = *(const bf16x8*)(Vs + vr * 32 + ((quad ^ (((vr >> 2) ^ vr) & 3))) * 8);
        oacc[qt][nt] = __builtin_amdgcn_mfma_f32_16x16x32_bf16(pf, vf, oacc[qt][nt], 0, 0, 0);
      }
    }
  }

  unsigned short* P = kz ? ctxp1 : ctxp0;
#pragma unroll
  for (int qt = 0; qt < 2; ++qt)
#pragma unroll
    for (int nt = 0; nt < 4; ++nt) {
      const int d = nt * 16 + col;
#pragma unroll
      for (int r = 0; r < 4; ++r) {
        const int qq = q0 + (w * 2 + qt) * 16 + quad * 4 + r;
        P[((size_t)(b * 1024) + qq) * 1024 + h * 64 + d] = f2bf(oacc[qt][nt][r]);
      }
    }
}

extern "C" void kernel_launch(void* const* d_in, const int* in_sizes, int n_in,
                              void* d_out, int out_size, void* d_ws, size_t ws_size,
                              hipStream_t stream) {
  const float* x    = (const float*)d_in[0];
  const int*   mask = (const int*)d_in[1];
  const float* wq = (const float*)d_in[2];
  const float* bq = (const float*)d_in[3];
  const float* wk = (const float*)d_in[4];
  const float* bk = (const float*)d_in[5];
  const float* wv = (const float*)d_in[6];
  const float* bv = (const float*)d_in[7];
  const float* wo = (const float*)d_in[8];
  const float* bo = (const float*)d_in[9];
  const float* w1 = (const float*)d_in[10];
  const float* b1 = (const float*)d_in[11];
  const float* w2 = (const float*)d_in[12];
  const float* b2 = (const float*)d_in[13];
  const float* ln1a = (const float*)d_in[14];
  const float* ln1b = (const float*)d_in[15];
  const float* ln2a = (const float*)d_in[16];
  const float* ln2b = (const float*)d_in[17];
  float* out = (float*)d_out;
  char* W = (char*)d_ws;
  const size_t MB = 1u << 20;

  unsigned short* wqkvT = (unsigned short*)(W + 0 * MB);   // 6 MB [3072][1024]
  unsigned short* woT   = (unsigned short*)(W + 6 * MB);   // 2 MB
  unsigned char*  w1F8  = (unsigned char*)(W + 8 * MB);    // 4 MB [4096][1024]
  unsigned char*  w2F8  = (unsigned char*)(W + 16 * MB);   // 4 MB [1024][4096]
  float*          bqkv  = (float*)(W + 24 * MB);           // 12 KB
  float*          corr  = (float*)(W + 24 * MB + 65536);   // 16 KB
  unsigned short* xn    = (unsigned short*)(W + 25 * MB);  // 8 MB bf16
  unsigned char*  xn2f8 = (unsigned char*)(W + 25 * MB);   // 4 MB (xn dead)
  unsigned short* qkb   = (unsigned short*)(W + 33 * MB);  // 16 MB [4096][2048]
  unsigned short* vT    = (unsigned short*)(W + 49 * MB);  // 8 MB [1024][4096]
  unsigned short* ctxp0 = (unsigned short*)(W + 57 * MB);  // 8 MB
  unsigned short* ctxp1 = (unsigned short*)(W + 65 * MB);  // 8 MB
  unsigned short* ctx   = (unsigned short*)(W + 33 * MB);  // 8 MB (qkb dead)
  unsigned short* x1    = (unsigned short*)(W + 73 * MB);  // 8 MB bf16
  unsigned char*  hbF8  = (unsigned char*)(W + 49 * MB);   // 16 MB (vT/ctxp0 dead)

  // weights + qkv bias + LN1 in one launch
  wconv_ln_kernel<<<7169, 256, 0, stream>>>(wq, wk, wv, wo, w1, w2, bq, bk, bv,
                                            wqkvT, woT, w1F8, w2F8, bqkv,
                                            x, xn, ln1a, ln1b);
  // fused q|k|v GEMM (bf16), v transposed into vT. 768 blocks, BK=64.
  mfma_gemm<128, 128, true, false, false, true, 12, 8>
      <<<dim3(24, 32), 256, 0, stream>>>(
      xn, wqkvT, bqkv, nullptr, qkb, vT, 2048, 1024, 1024, 1024);
  masksum_kernel<<<1024, 256, 0, stream>>>(vT, mask, corr);
  // attention, key-split kz=2: 1024 blocks (4/CU)
  attn_kernel<<<dim3(8, 16, 8), 256, 0, stream>>>(qkb, vT, mask, ctxp0, ctxp1);
  attn_combine_kernel<<<4096, 256, 0, stream>>>(ctxp0, ctxp1, corr, ctx);
  // wo-proj z=1, TM128xTN64 (512 blocks), epilogue: +bo +x -> x1 bf16
  mfma_gemm<128, 64, true, false, true, false, 8, 8>
      <<<dim3(16, 32), 256, 0, stream>>>(
      ctx, woT, bo, x, x1, nullptr, 1024, 1024, 1024, 1024);
  // LN2: x1 -> xn2 fp8
  ln2_kernel<<<4096, 256, 0, stream>>>(x1, ln2a, ln2b, xn2f8);
  // FFN1 fp8: 1024 blocks, BK=128, relu -> fp8 hb
  mfma_gemm_fp8<true, 128, 16, 8><<<dim3(32, 32), 256, 0, stream>>>(
      xn2f8, w1F8, b1, nullptr, hbF8, 4096, 1024, 1024, 1024);
  // FFN2 fp8 z=1, TM128xTN64 (512 blocks), K=4096; epilogue: +b2 +x1 -> out
  mfma_gemm_fp8<false, 64, 8, 8><<<dim3(16, 32), 256, 0, stream>>>(
      hbF8, w2F8, b2, x1, out, 1024, 4096, 4096, 4096);
}

// Round 14
// 277.616 us; speedup vs baseline: 1.2593x; 1.0280x over previous
//
#include <hip/hip_runtime.h>
#include <hip/hip_bf16.h>
#include <math.h>

// ---------------------------------------------------------------------------
// EncoderBlock, round 14: dispatch fusion.
//  - masksum merged into the attention launch (grid z 8->16; z>=8 blocks do
//    the coalesced masked-V reduction). Independent given vT; corr consumed
//    only by attn_combine. -1 dispatch, masksum hidden under attn.
//  - everything else byte-identical to round 13 (fp8 FFN z=1, fused
//    epilogues, VSPLIT qkv, region swizzles).
// ---------------------------------------------------------------------------

#define EPS 1e-5f

typedef __attribute__((ext_vector_type(8))) short bf16x8;
typedef __attribute__((ext_vector_type(4))) float f32x4;
typedef __attribute__((ext_vector_type(8))) int i32x8;
typedef __attribute__((ext_vector_type(4))) int i32x4;

typedef const __attribute__((address_space(1))) unsigned char glob_byte;
typedef __attribute__((address_space(3))) unsigned char lds_byte;

__device__ __forceinline__ void g2l16(const void* g, void* l) {
  __builtin_amdgcn_global_load_lds((glob_byte*)g, (lds_byte*)l, 16, 0, 0);
}

__device__ __forceinline__ unsigned short f2bf(float f) {
  union { float f; unsigned int u; } v; v.f = f;
  return (unsigned short)((v.u + 0x7FFFu + ((v.u >> 16) & 1u)) >> 16);
}
__device__ __forceinline__ float bf2f(unsigned short b) {
  union { unsigned int u; float f; } v; v.u = (unsigned int)b << 16;
  return v.f;
}
__device__ __forceinline__ unsigned int fbits(float f) {
  union { float f; unsigned int u; } v; v.f = f;
  return v.u;
}
__device__ __forceinline__ unsigned int pk_fp8x4(float a, float b, float c, float d) {
  unsigned int p = 0;
  p = __builtin_amdgcn_cvt_pk_fp8_f32(a, b, p, false);
  p = __builtin_amdgcn_cvt_pk_fp8_f32(c, d, p, true);
  return p;
}

// ---- weights: wq..wo -> bf16 [N][K]; w1/w2 -> fp8 [N][K]; qkv bias; LN1.
__global__ __launch_bounds__(256) void wconv_ln_kernel(
    const float* __restrict__ wq, const float* __restrict__ wk,
    const float* __restrict__ wv, const float* __restrict__ wo,
    const float* __restrict__ w1, const float* __restrict__ w2,
    const float* __restrict__ bq, const float* __restrict__ bk,
    const float* __restrict__ bv,
    unsigned short* __restrict__ wqkvT, unsigned short* __restrict__ woT,
    unsigned char* __restrict__ w1F8, unsigned char* __restrict__ w2F8,
    float* __restrict__ bqkv,
    const float* __restrict__ x, unsigned short* __restrict__ xn,
    const float* __restrict__ ln1a, const float* __restrict__ ln1b) {
  __shared__ float tile[64][65];
  const int bid = blockIdx.x;
  const int t = threadIdx.x;
  if (bid >= 3073) {  // ---- LayerNorm1 (torch: ddof=1, /(std+eps))
    const int row = bid - 3073;
    const float4 v = ((const float4*)(x + (size_t)row * 1024))[t];
    float s  = v.x + v.y + v.z + v.w;
    float ss = v.x * v.x + v.y * v.y + v.z * v.z + v.w * v.w;
#pragma unroll
    for (int off = 32; off > 0; off >>= 1) {
      s  += __shfl_down(s, off, 64);
      ss += __shfl_down(ss, off, 64);
    }
    __shared__ float red[8];
    const int lane = t & 63, wv_ = t >> 6;
    if (lane == 0) { red[wv_] = s; red[4 + wv_] = ss; }
    __syncthreads();
    const float S  = red[0] + red[1] + red[2] + red[3];
    const float SS = red[4] + red[5] + red[6] + red[7];
    const float mean = S * (1.0f / 1024.0f);
    float var = (SS - 1024.0f * mean * mean) * (1.0f / 1023.0f);
    var = fmaxf(var, 0.0f);
    const float scl = ln1a[0] / (sqrtf(var) + EPS);
    const float b = ln1b[0];
    ushort4 o;
    o.x = f2bf((v.x - mean) * scl + b);
    o.y = f2bf((v.y - mean) * scl + b);
    o.z = f2bf((v.z - mean) * scl + b);
    o.w = f2bf((v.w - mean) * scl + b);
    ((ushort4*)(xn + (size_t)row * 1024))[t] = o;
    return;
  }
  if (bid == 3072) {
#pragma unroll
    for (int i = 0; i < 12; ++i) {
      const int n = i * 256 + t;
      bqkv[n] = n < 1024 ? bq[n] : (n < 2048 ? bk[n - 1024] : bv[n - 2048]);
    }
    return;
  }
  const float* src; int K, N, tk, tn;
  unsigned short* dst16 = nullptr; unsigned char* dst8 = nullptr;
  if (bid < 1024) {
    const int m = bid >> 8, loc = bid & 255;
    src = m == 0 ? wq : m == 1 ? wk : m == 2 ? wv : wo;
    dst16 = m == 3 ? woT : (wqkvT + (size_t)m * 1024 * 1024);
    K = 1024; N = 1024; tk = loc >> 4; tn = loc & 15;
  } else if (bid < 2048) {
    const int loc = bid - 1024; src = w1; dst8 = w1F8;
    K = 1024; N = 4096; tk = loc >> 6; tn = loc & 63;
  } else {
    const int loc = bid - 2048; src = w2; dst8 = w2F8;
    K = 4096; N = 1024; tk = loc >> 4; tn = loc & 15;
  }
  const int lr = t >> 4, lc = (t & 15) * 4;
#pragma unroll
  for (int i = 0; i < 4; ++i) {
    const float4 v = *(const float4*)(src + (size_t)(tk * 64 + lr + 16 * i) * N + tn * 64 + lc);
    tile[lr + 16 * i][lc + 0] = v.x;
    tile[lr + 16 * i][lc + 1] = v.y;
    tile[lr + 16 * i][lc + 2] = v.z;
    tile[lr + 16 * i][lc + 3] = v.w;
  }
  __syncthreads();
  const int on = t >> 2, ok = (t & 3) * 16;
#pragma unroll
  for (int jj = 0; jj < 4; ++jj) {
    if (dst8) {
      const unsigned int p = pk_fp8x4(tile[ok + 4 * jj + 0][on], tile[ok + 4 * jj + 1][on],
                                      tile[ok + 4 * jj + 2][on], tile[ok + 4 * jj + 3][on]);
      *(unsigned int*)(dst8 + (size_t)(tn * 64 + on) * K + tk * 64 + ok + 4 * jj) = p;
    } else {
      ushort4 o4;
      o4.x = f2bf(tile[ok + 4 * jj + 0][on]);
      o4.y = f2bf(tile[ok + 4 * jj + 1][on]);
      o4.z = f2bf(tile[ok + 4 * jj + 2][on]);
      o4.w = f2bf(tile[ok + 4 * jj + 3][on]);
      *(ushort4*)(dst16 + (size_t)(tn * 64 + on) * K + tk * 64 + ok + 4 * jj) = o4;
    }
  }
}

// ---- bf16 MFMA GEMM, BK=64, TMxTN, z=1 (round 13).
template <int TM, int TN, bool OUT_BF16, bool RELU, bool RES, bool VSPLIT,
          int RX, int RY>
__global__ __launch_bounds__(256, 4) void mfma_gemm(
    const unsigned short* __restrict__ A, const unsigned short* __restrict__ Bt,
    const float* __restrict__ bias, const float* __restrict__ res,
    void* __restrict__ C0, void* __restrict__ C1,
    int N, int lda, int ldb, int KH) {
  constexpr int WM = 2, WN = 2;
  constexpr int MSPAN = TM / WM, NSPAN = TN / WN;
  constexpr int MI = MSPAN / 16, NJ = NSPAN / 16;
  __shared__ __align__(16) unsigned short As[TM * 64];
  __shared__ __align__(16) unsigned short Bs[TN * 64];
  const int tid = threadIdx.x, lane = tid & 63;
  const int w = tid >> 6;
  const int quad = lane >> 4, col = lane & 15;
  const int wm = w % WM, wn = w / WM;

  int bx = blockIdx.x, by = blockIdx.y;
  {
    const int gx = gridDim.x;
    const int L = bx + gx * by;
    const int r = L & 7, s = L >> 3;
    const int nrx = gx / RX;
    const int rx = r % nrx, ry = r / nrx;
    bx = rx * RX + s % RX;
    by = ry * RY + (s / RX) % RY;
  }
  const int m0 = by * TM, n0 = bx * TN;

  f32x4 acc[MI][NJ];
  const f32x4 z4 = {0.f, 0.f, 0.f, 0.f};
#pragma unroll
  for (int i = 0; i < MI; ++i)
#pragma unroll
    for (int j = 0; j < NJ; ++j) acc[i][j] = z4;

  for (int k0 = 0; k0 < KH; k0 += 64) {
    __syncthreads();
#pragma unroll
    for (int t = 0; t < TM / 32; ++t) {
      const int s = t * 256 + tid;
      const int r = s >> 3, c = (s & 7) ^ (r & 7);
      g2l16(A + (size_t)(m0 + r) * lda + k0 + c * 8, (void*)(As + s * 8));
    }
#pragma unroll
    for (int t = 0; t < TN / 32; ++t) {
      const int s = t * 256 + tid;
      const int r = s >> 3, c = (s & 7) ^ (r & 7);
      g2l16(Bt + (size_t)(n0 + r) * ldb + k0 + c * 8, (void*)(Bs + s * 8));
    }
    __syncthreads();
#pragma unroll
    for (int h = 0; h < 2; ++h) {
      bf16x8 af[MI], bfr[NJ];
#pragma unroll
      for (int i = 0; i < MI; ++i) {
        const int rr = wm * MSPAN + i * 16 + col;
        af[i] = *(const bf16x8*)(As + rr * 64 + (((h << 2) | quad) ^ (rr & 7)) * 8);
      }
#pragma unroll
      for (int j = 0; j < NJ; ++j) {
        const int rr = wn * NSPAN + j * 16 + col;
        bfr[j] = *(const bf16x8*)(Bs + rr * 64 + (((h << 2) | quad) ^ (rr & 7)) * 8);
      }
#pragma unroll
      for (int i = 0; i < MI; ++i)
#pragma unroll
        for (int j = 0; j < NJ; ++j)
          acc[i][j] = __builtin_amdgcn_mfma_f32_16x16x32_bf16(af[i], bfr[j], acc[i][j], 0, 0, 0);
    }
  }
#pragma unroll
  for (int i = 0; i < MI; ++i) {
    const int mrow = m0 + wm * MSPAN + i * 16 + quad * 4;
#pragma unroll
    for (int j = 0; j < NJ; ++j) {
      const int n = n0 + wn * NSPAN + j * 16 + col;
      const float bn = bias[n];
      if (VSPLIT && n0 >= 2048) {
        ushort4 o4;
        o4.x = f2bf(acc[i][j][0] + bn);
        o4.y = f2bf(acc[i][j][1] + bn);
        o4.z = f2bf(acc[i][j][2] + bn);
        o4.w = f2bf(acc[i][j][3] + bn);
        *(ushort4*)((unsigned short*)C1 + (size_t)(n - 2048) * 4096 + mrow) = o4;
        continue;
      }
#pragma unroll
      for (int r = 0; r < 4; ++r) {
        const int m = mrow + r;
        float v = acc[i][j][r] + bn;
        if (RES)  v += res[(size_t)m * N + n];
        if (RELU) v = fmaxf(v, 0.f);
        if (OUT_BF16) ((unsigned short*)C0)[(size_t)m * N + n] = f2bf(v);
        else          ((float*)C0)[(size_t)m * N + n] = v;
      }
    }
  }
}

// ---- MX-fp8 MFMA GEMM, TM=128 x TN, BK=128, z=1 (round 13).
template <bool FP8OUT, int TN, int RX, int RY>
__global__ __launch_bounds__(256, 4) void mfma_gemm_fp8(
    const unsigned char* __restrict__ A, const unsigned char* __restrict__ Bt,
    const float* __restrict__ bias, const unsigned short* __restrict__ res16,
    void* __restrict__ C0, int N, int lda, int ldb, int KH) {
  constexpr int NSPAN = TN / 2;
  constexpr int NJ = NSPAN / 16;
  __shared__ __align__(16) unsigned char As[128 * 128];
  __shared__ __align__(16) unsigned char Bs[TN * 128];
  const int tid = threadIdx.x, lane = tid & 63;
  const int w = tid >> 6;
  const int quad = lane >> 4, col = lane & 15;
  const int wm = w & 1, wn = w >> 1;

  int bx = blockIdx.x, by = blockIdx.y;
  {
    const int gx = gridDim.x;
    const int L = bx + gx * by;
    const int r = L & 7, s = L >> 3;
    const int nrx = gx / RX;
    const int rx = r % nrx, ry = r / nrx;
    bx = rx * RX + s % RX;
    by = ry * RY + (s / RX) % RY;
  }
  const int m0 = by * 128, n0 = bx * TN;

  f32x4 acc[4][NJ];
  const f32x4 z4 = {0.f, 0.f, 0.f, 0.f};
#pragma unroll
  for (int i = 0; i < 4; ++i)
#pragma unroll
    for (int j = 0; j < NJ; ++j) acc[i][j] = z4;

  for (int k0 = 0; k0 < KH; k0 += 128) {
    __syncthreads();
#pragma unroll
    for (int t = 0; t < 4; ++t) {
      const int s = t * 256 + tid;
      const int r = s >> 3, c = (s & 7) ^ (r & 7);
      g2l16(A + (size_t)(m0 + r) * lda + k0 + c * 16, (void*)(As + s * 16));
    }
#pragma unroll
    for (int t = 0; t < TN / 32; ++t) {
      const int s = t * 256 + tid;
      const int r = s >> 3, c = (s & 7) ^ (r & 7);
      g2l16(Bt + (size_t)(n0 + r) * ldb + k0 + c * 16, (void*)(Bs + s * 16));
    }
    __syncthreads();
    i32x8 af[4];
#pragma unroll
    for (int i = 0; i < 4; ++i) {
      const int rr = wm * 64 + i * 16 + col;
      const i32x4* rowp = (const i32x4*)(As + rr * 128);
      const i32x4 lo = rowp[(2 * quad) ^ (rr & 7)];
      const i32x4 hi = rowp[(2 * quad + 1) ^ (rr & 7)];
      af[i] = __builtin_shufflevector(lo, hi, 0, 1, 2, 3, 4, 5, 6, 7);
    }
#pragma unroll
    for (int j = 0; j < NJ; ++j) {
      const int rr = wn * NSPAN + j * 16 + col;
      const i32x4* rowp = (const i32x4*)(Bs + rr * 128);
      const i32x4 lo = rowp[(2 * quad) ^ (rr & 7)];
      const i32x4 hi = rowp[(2 * quad + 1) ^ (rr & 7)];
      const i32x8 bfj = __builtin_shufflevector(lo, hi, 0, 1, 2, 3, 4, 5, 6, 7);
#pragma unroll
      for (int i = 0; i < 4; ++i)
        acc[i][j] = __builtin_amdgcn_mfma_scale_f32_16x16x128_f8f6f4(
            af[i], bfj, acc[i][j], 0, 0, 0, 0x7F7F7F7Fu, 0, 0x7F7F7F7Fu);
    }
  }
#pragma unroll
  for (int i = 0; i < 4; ++i) {
    const int mrow = m0 + wm * 64 + i * 16 + quad * 4;
#pragma unroll
    for (int j = 0; j < NJ; ++j) {
      const int n = n0 + wn * NSPAN + j * 16 + col;
      const float bn = bias[n];
#pragma unroll
      for (int r = 0; r < 4; ++r) {
        const int m = mrow + r;
        if (FP8OUT) {
          const float v = fmaxf(acc[i][j][r] + bn, 0.f);
          const unsigned int p = __builtin_amdgcn_cvt_pk_fp8_f32(v, v, 0, false);
          ((unsigned char*)C0)[(size_t)m * N + n] = (unsigned char)(p & 0xFF);
        } else {
          const float v = acc[i][j][r] + bn + bf2f(res16[(size_t)m * N + n]);
          ((float*)C0)[(size_t)m * N + n] = v;
        }
      }
    }
  }
}

// ---- LN2: x1 bf16 -> xn2 fp8 (torch semantics).
__global__ __launch_bounds__(256) void ln2_kernel(
    const unsigned short* __restrict__ x1,
    const float* __restrict__ alpha, const float* __restrict__ beta,
    unsigned char* __restrict__ xn2f8) {
  const int row = blockIdx.x, t = threadIdx.x;
  const size_t i = (size_t)row * 256 + t;
  const ushort4 a4 = ((const ushort4*)x1)[i];
  float4 v;
  v.x = bf2f(a4.x); v.y = bf2f(a4.y); v.z = bf2f(a4.z); v.w = bf2f(a4.w);
  float s  = v.x + v.y + v.z + v.w;
  float ss = v.x * v.x + v.y * v.y + v.z * v.z + v.w * v.w;
#pragma unroll
  for (int off = 32; off > 0; off >>= 1) {
    s  += __shfl_down(s, off, 64);
    ss += __shfl_down(ss, off, 64);
  }
  __shared__ float red[8];
  const int lane = t & 63, wv_ = t >> 6;
  if (lane == 0) { red[wv_] = s; red[4 + wv_] = ss; }
  __syncthreads();
  const float S  = red[0] + red[1] + red[2] + red[3];
  const float SS = red[4] + red[5] + red[6] + red[7];
  const float mean = S * (1.0f / 1024.0f);
  float var = (SS - 1024.0f * mean * mean) * (1.0f / 1023.0f);
  var = fmaxf(var, 0.0f);
  const float scl = alpha[0] / (sqrtf(var) + EPS);
  const float bb = beta[0];
  ((unsigned int*)xn2f8)[i] = pk_fp8x4((v.x - mean) * scl + bb,
                                       (v.y - mean) * scl + bb,
                                       (v.z - mean) * scl + bb,
                                       (v.w - mean) * scl + bb);
}

// ---- combine attention key-halves + corr -> ctx (bf16)
__global__ __launch_bounds__(256) void attn_combine_kernel(
    const unsigned short* __restrict__ p0, const unsigned short* __restrict__ p1,
    const float* __restrict__ corr, unsigned short* __restrict__ ctx) {
  const int row = blockIdx.x, t = threadIdx.x;
  const size_t i = (size_t)row * 256 + t;
  const ushort4 a4 = ((const ushort4*)p0)[i];
  const ushort4 b4 = ((const ushort4*)p1)[i];
  const float4 c4 = ((const float4*)(corr + (row >> 10) * 1024))[t];
  ushort4 o;
  o.x = f2bf(bf2f(a4.x) + bf2f(b4.x) - 1e9f * c4.x);
  o.y = f2bf(bf2f(a4.y) + bf2f(b4.y) - 1e9f * c4.y);
  o.z = f2bf(bf2f(a4.z) + bf2f(b4.z) - 1e9f * c4.z);
  o.w = f2bf(bf2f(a4.w) + bf2f(b4.w) - 1e9f * c4.w);
  ((ushort4*)ctx)[i] = o;
}

// ---- fused attention (kz=2) + masksum in ONE launch.
// grid (8,16,16): z<8 -> attention blocks (id space identical to round 13);
// z>=8 -> 1024 masksum blocks (coalesced masked-V reduction -> corr).
__global__ __launch_bounds__(256, 4) void attn_masksum_kernel(
    const unsigned short* __restrict__ qkb, const unsigned short* __restrict__ vT,
    const int* __restrict__ mask,
    unsigned short* __restrict__ ctxp0, unsigned short* __restrict__ ctxp1,
    float* __restrict__ corr) {
  __shared__ __align__(16) unsigned short Qs[128 * 64];
  __shared__ __align__(16) unsigned short Ks[32 * 64];
  __shared__ __align__(16) unsigned short Vs[64 * 32];
  __shared__ __align__(16) unsigned short Ps[128 * 40];
  __shared__ float redm[4][4];
  const int tid = threadIdx.x, lane = tid & 63, w = tid >> 6;

  if (blockIdx.z >= 8) {
    // ---- masksum role: corr[b*1024+hd] = sum_{tok: mask==0} V[tok][hd]
    const int hd = blockIdx.x + 8 * (blockIdx.y + 16 * (blockIdx.z - 8));
    const int t = tid;
    float sb[4];
#pragma unroll
    for (int b = 0; b < 4; ++b) {
      const ushort4 v4 = *(const ushort4*)(vT + (size_t)hd * 4096 + b * 1024 + t * 4);
      const int4 m4 = *(const int4*)(mask + b * 1024 + t * 4);
      float s = 0.f;
      if (m4.x == 0) s += bf2f(v4.x);
      if (m4.y == 0) s += bf2f(v4.y);
      if (m4.z == 0) s += bf2f(v4.z);
      if (m4.w == 0) s += bf2f(v4.w);
#pragma unroll
      for (int off = 32; off > 0; off >>= 1) s += __shfl_down(s, off, 64);
      sb[b] = s;
    }
    if (lane == 0) {
      redm[w][0] = sb[0]; redm[w][1] = sb[1]; redm[w][2] = sb[2]; redm[w][3] = sb[3];
    }
    __syncthreads();
    if (t < 4)
      corr[t * 1024 + hd] = redm[0][t] + redm[1][t] + redm[2][t] + redm[3][t];
    return;
  }

  const int quad = lane >> 4, col = lane & 15;
  const int L = blockIdx.x + 8 * (blockIdx.y + 16 * blockIdx.z);  // 0..1023
  const int s_ = L >> 3;
  const int g = (L & 7) * 16 + (s_ >> 3);
  const int q0 = (s_ & 7) * 128;
  const int h = g & 15, bkz = g >> 4;
  const int b = bkz >> 1, kz = bkz & 1;
  const size_t qbase = ((size_t)(b * 1024 + q0)) * 2048 + h * 64;

#pragma unroll
  for (int t = 0; t < 4; ++t) {
    const int s = t * 256 + w * 64 + lane;
    const int m = s >> 3, c = (s & 7) ^ (m & 7);
    g2l16(qkb + qbase + (size_t)m * 2048 + c * 8, (void*)(Qs + s * 8));
  }
  __syncthreads();
  bf16x8 qf[2][2];
#pragma unroll
  for (int qt = 0; qt < 2; ++qt)
#pragma unroll
    for (int kf = 0; kf < 2; ++kf) {
      const int m = (w * 2 + qt) * 16 + col;
      const int c = (kf * 4 + quad) ^ (m & 7);
      qf[qt][kf] = *(const bf16x8*)(Qs + m * 64 + c * 8);
    }

  const f32x4 z4 = {0.f, 0.f, 0.f, 0.f};
  f32x4 oacc[2][4];
#pragma unroll
  for (int qt = 0; qt < 2; ++qt)
#pragma unroll
    for (int nt = 0; nt < 4; ++nt) oacc[qt][nt] = z4;

  const int* mrow = mask + b * 1024;
  const int kb0 = kz * 512;
  for (int kb = kb0; kb < kb0 + 512; kb += 32) {
    __syncthreads();
    {
      const int s = w * 64 + lane;
      const int key = s >> 3, ck = (s & 7) ^ (key & 7);
      g2l16(qkb + ((size_t)(b * 1024 + kb + key)) * 2048 + 1024 + h * 64 + ck * 8,
            (void*)(Ks + s * 8));
      const int d = s >> 2, cv = (s & 3) ^ (((d >> 2) ^ d) & 3);
      g2l16(vT + ((size_t)(h * 64 + d)) * 4096 + b * 1024 + kb + cv * 8,
            (void*)(Vs + s * 8));
    }
    __syncthreads();

    f32x4 st[2][2];
#pragma unroll
    for (int qt = 0; qt < 2; ++qt)
#pragma unroll
      for (int kt = 0; kt < 2; ++kt) st[qt][kt] = z4;
#pragma unroll
    for (int kt = 0; kt < 2; ++kt)
#pragma unroll
      for (int kf = 0; kf < 2; ++kf) {
        const int key = kt * 16 + col;
        const int c = (kf * 4 + quad) ^ (key & 7);
        const bf16x8 kfrag = *(const bf16x8*)(Ks + key * 64 + c * 8);
#pragma unroll
        for (int qt = 0; qt < 2; ++qt)
          st[qt][kt] = __builtin_amdgcn_mfma_f32_16x16x32_bf16(
              kfrag, qf[qt][kf], st[qt][kt], 0, 0, 0);
      }

    const int4 mv0 = *(const int4*)(mrow + kb + quad * 4);
    const int4 mv1 = *(const int4*)(mrow + kb + 16 + quad * 4);
#pragma unroll
    for (int qt = 0; qt < 2; ++qt) {
      const int qrow = (w * 2 + qt) * 16 + col;
#pragma unroll
      for (int kt = 0; kt < 2; ++kt) {
        const int4 mv = kt ? mv1 : mv0;
        const f32x4 sv = st[qt][kt];
        const unsigned int u0 = fbits((mv.x ? 0.125f : 0.f) * sv[0]) + 0x8000u;
        const unsigned int u1 = fbits((mv.y ? 0.125f : 0.f) * sv[1]) + 0x8000u;
        const unsigned int u2 = fbits((mv.z ? 0.125f : 0.f) * sv[2]) + 0x8000u;
        const unsigned int u3 = fbits((mv.w ? 0.125f : 0.f) * sv[3]) + 0x8000u;
        uint2 pk;
        pk.x = (u0 >> 16) | (u1 & 0xFFFF0000u);
        pk.y = (u2 >> 16) | (u3 & 0xFFFF0000u);
        const int pp = kt * 2 + (quad >> 1);
        *(uint2*)(Ps + qrow * 40 + ((pp ^ (qrow & 3)) * 8 + (quad & 1) * 4)) = pk;
      }
    }
    // no barrier: wave w only touches its own q-rows

#pragma unroll
    for (int qt = 0; qt < 2; ++qt) {
      const int qrow = (w * 2 + qt) * 16 + col;
      const bf16x8 pf = *(const bf16x8*)(Ps + qrow * 40 + (quad ^ (qrow & 3)) * 8);
#pragma unroll
      for (int nt = 0; nt < 4; ++nt) {
        const int vr = nt * 16 + col;
        const bf16x8 vf = *(const bf16x8*)(Vs + vr * 32 + ((quad ^ (((vr >> 2) ^ vr) & 3))) * 8);
        oacc[qt][nt] = __builtin_amdgcn_mfma_f32_16x16x32_bf16(pf, vf, oacc[qt][nt], 0, 0, 0);
      }
    }
  }

  unsigned short* P = kz ? ctxp1 : ctxp0;
#pragma unroll
  for (int qt = 0; qt < 2; ++qt)
#pragma unroll
    for (int nt = 0; nt < 4; ++nt) {
      const int d = nt * 16 + col;
#pragma unroll
      for (int r = 0; r < 4; ++r) {
        const int qq = q0 + (w * 2 + qt) * 16 + quad * 4 + r;
        P[((size_t)(b * 1024) + qq) * 1024 + h * 64 + d] = f2bf(oacc[qt][nt][r]);
      }
    }
}

extern "C" void kernel_launch(void* const* d_in, const int* in_sizes, int n_in,
                              void* d_out, int out_size, void* d_ws, size_t ws_size,
                              hipStream_t stream) {
  const float* x    = (const float*)d_in[0];
  const int*   mask = (const int*)d_in[1];
  const float* wq = (const float*)d_in[2];
  const float* bq = (const float*)d_in[3];
  const float* wk = (const float*)d_in[4];
  const float* bk = (const float*)d_in[5];
  const float* wv = (const float*)d_in[6];
  const float* bv = (const float*)d_in[7];
  const float* wo = (const float*)d_in[8];
  const float* bo = (const float*)d_in[9];
  const float* w1 = (const float*)d_in[10];
  const float* b1 = (const float*)d_in[11];
  const float* w2 = (const float*)d_in[12];
  const float* b2 = (const float*)d_in[13];
  const float* ln1a = (const float*)d_in[14];
  const float* ln1b = (const float*)d_in[15];
  const float* ln2a = (const float*)d_in[16];
  const float* ln2b = (const float*)d_in[17];
  float* out = (float*)d_out;
  char* W = (char*)d_ws;
  const size_t MB = 1u << 20;

  unsigned short* wqkvT = (unsigned short*)(W + 0 * MB);   // 6 MB [3072][1024]
  unsigned short* woT   = (unsigned short*)(W + 6 * MB);   // 2 MB
  unsigned char*  w1F8  = (unsigned char*)(W + 8 * MB);    // 4 MB [4096][1024]
  unsigned char*  w2F8  = (unsigned char*)(W + 16 * MB);   // 4 MB [1024][4096]
  float*          bqkv  = (float*)(W + 24 * MB);           // 12 KB
  float*          corr  = (float*)(W + 24 * MB + 65536);   // 16 KB
  unsigned short* xn    = (unsigned short*)(W + 25 * MB);  // 8 MB bf16
  unsigned char*  xn2f8 = (unsigned char*)(W + 25 * MB);   // 4 MB (xn dead)
  unsigned short* qkb   = (unsigned short*)(W + 33 * MB);  // 16 MB [4096][2048]
  unsigned short* vT    = (unsigned short*)(W + 49 * MB);  // 8 MB [1024][4096]
  unsigned short* ctxp0 = (unsigned short*)(W + 57 * MB);  // 8 MB
  unsigned short* ctxp1 = (unsigned short*)(W + 65 * MB);  // 8 MB
  unsigned short* ctx   = (unsigned short*)(W + 33 * MB);  // 8 MB (qkb dead)
  unsigned short* x1    = (unsigned short*)(W + 73 * MB);  // 8 MB bf16
  unsigned char*  hbF8  = (unsigned char*)(W + 49 * MB);   // 16 MB (vT/ctxp0 dead)

  // weights + qkv bias + LN1 in one launch
  wconv_ln_kernel<<<7169, 256, 0, stream>>>(wq, wk, wv, wo, w1, w2, bq, bk, bv,
                                            wqkvT, woT, w1F8, w2F8, bqkv,
                                            x, xn, ln1a, ln1b);
  // fused q|k|v GEMM (bf16), v transposed into vT. 768 blocks, BK=64.
  mfma_gemm<128, 128, true, false, false, true, 12, 8>
      <<<dim3(24, 32), 256, 0, stream>>>(
      xn, wqkvT, bqkv, nullptr, qkb, vT, 2048, 1024, 1024, 1024);
  // attention (kz=2, 1024 blocks) + masksum (1024 blocks) in ONE launch
  attn_masksum_kernel<<<dim3(8, 16, 16), 256, 0, stream>>>(
      qkb, vT, mask, ctxp0, ctxp1, corr);
  attn_combine_kernel<<<4096, 256, 0, stream>>>(ctxp0, ctxp1, corr, ctx);
  // wo-proj z=1, TM128xTN64 (512 blocks), epilogue: +bo +x -> x1 bf16
  mfma_gemm<128, 64, true, false, true, false, 8, 8>
      <<<dim3(16, 32), 256, 0, stream>>>(
      ctx, woT, bo, x, x1, nullptr, 1024, 1024, 1024, 1024);
  // LN2: x1 -> xn2 fp8
  ln2_kernel<<<4096, 256, 0, stream>>>(x1, ln2a, ln2b, xn2f8);
  // FFN1 fp8: 1024 blocks, BK=128, relu -> fp8 hb
  mfma_gemm_fp8<true, 128, 16, 8><<<dim3(32, 32), 256, 0, stream>>>(
      xn2f8, w1F8, b1, nullptr, hbF8, 4096, 1024, 1024, 1024);
  // FFN2 fp8 z=1, TM128xTN64 (512 blocks), K=4096; epilogue: +b2 +x1 -> out
  mfma_gemm_fp8<false, 64, 8, 8><<<dim3(16, 32), 256, 0, stream>>>(
      hbF8, w2F8, b2, x1, out, 1024, 4096, 4096, 4096);
}